// Round 1
// baseline (571.225 us; speedup 1.0000x reference)
//
#include <hip/hip_runtime.h>
#include <hip/hip_bf16.h>
#include <math.h>

#define NQ     16384
#define CDIM   256
#define NHEADS 8
#define NPTS   8
#define NLVL   2
#define HH     128
#define WWID   128
#define DHEAD  32

typedef __bf16 bf16_t;
typedef __bf16 bf16x8 __attribute__((ext_vector_type(8)));
typedef __bf16 bf16x4 __attribute__((ext_vector_type(4)));
typedef float  f32x4  __attribute__((ext_vector_type(4)));

__device__ __forceinline__ bf16_t f2b(float f) { return (bf16_t)f; }

// ---------------------------------------------------------------------------
// q = bf16(query + query_pos), vectorized x4
// ---------------------------------------------------------------------------
__global__ __launch_bounds__(256) void addcvt_k(const float* __restrict__ a,
                                                const float* __restrict__ b,
                                                bf16_t* __restrict__ o, int n) {
    int i = (blockIdx.x * 256 + threadIdx.x) * 4;
    if (i >= n) return;
    float4 av = *reinterpret_cast<const float4*>(a + i);
    float4 bv = *reinterpret_cast<const float4*>(b + i);
    bf16x4 ov;
    ov[0] = f2b(av.x + bv.x);
    ov[1] = f2b(av.y + bv.y);
    ov[2] = f2b(av.z + bv.z);
    ov[3] = f2b(av.w + bv.w);
    *reinterpret_cast<bf16x4*>(o + i) = ov;
}

// ---------------------------------------------------------------------------
// GEMM: C[M,N] = A[M,K] * B[K,N] + bias (+ addsrc). A bf16 (or fp32->bf16 on
// stage), B fp32 (converted on stage), MFMA 16x16x32 bf16, 64x64 tile,
// 4 waves (wave w owns rows 16w..16w+15, 4 col tiles of 16).
// ---------------------------------------------------------------------------
template <bool A_F32, bool OUT_BF16, bool ADD_SRC>
__global__ __launch_bounds__(256) void gemm_k(const void* __restrict__ Aptr,
                                              const float* __restrict__ B,
                                              const float* __restrict__ bias,
                                              const float* __restrict__ addsrc,
                                              void* __restrict__ Cout,
                                              int M, int N, int K) {
    __shared__ __align__(16) bf16_t As[64][40];  // pad 32->40 (80B row stride)
    __shared__ __align__(16) bf16_t Bs[64][40];  // transposed: [n][k]

    const int tid  = threadIdx.x;
    const int wave = tid >> 6;
    const int lane = tid & 63;
    const int rowBase = blockIdx.y * 64;
    const int colBase = blockIdx.x * 64;

    // staging indices
    const int ar = tid >> 2;        // 0..63 (A row)
    const int ak = (tid & 3) * 8;   // 0,8,16,24 (A k chunk)
    const int bk = tid >> 3;        // 0..31 (B k row)
    const int bn = (tid & 7) * 8;   // 0..56 (B n chunk)

    f32x4 acc[4] = {{0.f, 0.f, 0.f, 0.f}, {0.f, 0.f, 0.f, 0.f},
                    {0.f, 0.f, 0.f, 0.f}, {0.f, 0.f, 0.f, 0.f}};

    const int fr = lane & 15;
    const int fq = lane >> 4;

    for (int k0 = 0; k0 < K; k0 += 32) {
        __syncthreads();
        // --- stage A tile (64 x 32) ---
        if (A_F32) {
            const float* ap = (const float*)Aptr + (size_t)(rowBase + ar) * K + k0 + ak;
            float4 a0 = *reinterpret_cast<const float4*>(ap);
            float4 a1 = *reinterpret_cast<const float4*>(ap + 4);
            bf16x8 av;
            av[0] = f2b(a0.x); av[1] = f2b(a0.y); av[2] = f2b(a0.z); av[3] = f2b(a0.w);
            av[4] = f2b(a1.x); av[5] = f2b(a1.y); av[6] = f2b(a1.z); av[7] = f2b(a1.w);
            *reinterpret_cast<bf16x8*>(&As[ar][ak]) = av;
        } else {
            const bf16_t* ap = (const bf16_t*)Aptr + (size_t)(rowBase + ar) * K + k0 + ak;
            *reinterpret_cast<uint4*>(&As[ar][ak]) = *reinterpret_cast<const uint4*>(ap);
        }
        // --- stage B tile (32 x 64) transposed into Bs[n][k] ---
        {
            const float* bp = B + (size_t)(k0 + bk) * N + colBase + bn;
            float4 b0 = *reinterpret_cast<const float4*>(bp);
            float4 b1 = *reinterpret_cast<const float4*>(bp + 4);
            Bs[bn + 0][bk] = f2b(b0.x);
            Bs[bn + 1][bk] = f2b(b0.y);
            Bs[bn + 2][bk] = f2b(b0.z);
            Bs[bn + 3][bk] = f2b(b0.w);
            Bs[bn + 4][bk] = f2b(b1.x);
            Bs[bn + 5][bk] = f2b(b1.y);
            Bs[bn + 6][bk] = f2b(b1.z);
            Bs[bn + 7][bk] = f2b(b1.w);
        }
        __syncthreads();
        // --- compute ---
        bf16x8 afrag = *reinterpret_cast<const bf16x8*>(&As[wave * 16 + fr][fq * 8]);
#pragma unroll
        for (int t = 0; t < 4; ++t) {
            bf16x8 bfrag = *reinterpret_cast<const bf16x8*>(&Bs[t * 16 + fr][fq * 8]);
            acc[t] = __builtin_amdgcn_mfma_f32_16x16x32_bf16(afrag, bfrag, acc[t], 0, 0, 0);
        }
    }

    // --- epilogue: D[row = quad*4+reg][col = lane&15] ---
#pragma unroll
    for (int t = 0; t < 4; ++t) {
        const int col = colBase + t * 16 + fr;
        const float bv = bias[col];
#pragma unroll
        for (int r = 0; r < 4; ++r) {
            const int row = rowBase + wave * 16 + fq * 4 + r;
            float vv = acc[t][r] + bv;
            if (ADD_SRC) vv += addsrc[(size_t)row * N + col];
            if (OUT_BF16)
                ((bf16_t*)Cout)[(size_t)row * N + col] = f2b(vv);
            else
                ((float*)Cout)[(size_t)row * N + col] = vv;
        }
    }
}

// ---------------------------------------------------------------------------
// in-place softmax over contiguous groups of 16 (NQ*HEADS groups)
// ---------------------------------------------------------------------------
__global__ __launch_bounds__(256) void softmax16_k(float* __restrict__ a) {
    int g = blockIdx.x * 256 + threadIdx.x;
    if (g >= NQ * NHEADS) return;
    float* p = a + (size_t)g * 16;
    float e[16];
    float m = p[0];
#pragma unroll
    for (int i = 1; i < 16; ++i) m = fmaxf(m, p[i]);
    float s = 0.f;
#pragma unroll
    for (int i = 0; i < 16; ++i) { e[i] = __expf(p[i] - m); s += e[i]; }
    float inv = 1.f / s;
#pragma unroll
    for (int i = 0; i < 16; ++i) p[i] = e[i] * inv;
}

// ---------------------------------------------------------------------------
// Bilinear sampling + attention-weighted accumulation.
// Block = 1 query (8 heads x 32 dims). Thread: h = tid>>5, d = tid&31.
// ---------------------------------------------------------------------------
__device__ __forceinline__ float tap(const bf16_t* __restrict__ base, int x, int y) {
    if ((unsigned)x < (unsigned)WWID && (unsigned)y < (unsigned)HH)
        return (float)base[(size_t)(y * WWID + x) * CDIM];
    return 0.f;
}

__global__ __launch_bounds__(256) void sample_k(const bf16_t* __restrict__ v,
                                                const float* __restrict__ off,
                                                const float* __restrict__ attnw,
                                                const float* __restrict__ refp,
                                                bf16_t* __restrict__ tmp) {
    const int q = blockIdx.x;
    const int h = threadIdx.x >> 5;
    const int d = threadIdx.x & 31;

    float acc = 0.f;
#pragma unroll
    for (int l = 0; l < NLVL; ++l) {
        const float bx = refp[q * 4 + l * 2 + 0] * (float)WWID - 0.5f;
        const float by = refp[q * 4 + l * 2 + 1] * (float)HH - 0.5f;
        const bf16_t* base = v + (size_t)l * NQ * CDIM + h * DHEAD + d;
#pragma unroll
        for (int p = 0; p < NPTS; ++p) {
            const int oc = q * CDIM + h * 32 + l * 16 + p * 2;
            const float px = bx + off[oc];
            const float py = by + off[oc + 1];
            const float w = attnw[q * 128 + h * 16 + l * 8 + p];
            const float x0f = floorf(px), y0f = floorf(py);
            const int x0 = (int)x0f, y0 = (int)y0f;
            const float wx1 = px - x0f, wy1 = py - y0f;
            const float wx0 = 1.f - wx1, wy0 = 1.f - wy1;
            const float v00 = tap(base, x0, y0);
            const float v10 = tap(base, x0 + 1, y0);
            const float v01 = tap(base, x0, y0 + 1);
            const float v11 = tap(base, x0 + 1, y0 + 1);
            const float bil = (v00 * wx0 + v10 * wx1) * wy0 +
                              (v01 * wx0 + v11 * wx1) * wy1;
            acc = fmaf(w, bil, acc);
        }
    }
    tmp[(size_t)q * CDIM + h * DHEAD + d] = f2b(acc);
}

// ---------------------------------------------------------------------------
extern "C" void kernel_launch(void* const* d_in, const int* in_sizes, int n_in,
                              void* d_out, int out_size, void* d_ws, size_t ws_size,
                              hipStream_t stream) {
    const float* query     = (const float*)d_in[0];
    const float* query_pos = (const float*)d_in[1];
    const float* value     = (const float*)d_in[2];
    const float* refp      = (const float*)d_in[3];
    // d_in[4] spatial_shapes: static 128x128, hard-coded
    const float* W_off  = (const float*)d_in[5];
    const float* b_off  = (const float*)d_in[6];
    const float* W_attn = (const float*)d_in[7];
    const float* b_attn = (const float*)d_in[8];
    const float* W_val  = (const float*)d_in[9];
    const float* b_val  = (const float*)d_in[10];
    const float* W_out  = (const float*)d_in[11];
    const float* b_out  = (const float*)d_in[12];
    float* out = (float*)d_out;

    char* ws = (char*)d_ws;
    bf16_t* q_bf16 = (bf16_t*)(ws);                       //  8,388,608 B
    bf16_t* v_bf16 = (bf16_t*)(ws + 8388608);             // 16,777,216 B
    float*  c_off  = (float*)(ws + 25165824);             // 16,777,216 B
    float*  c_attn = (float*)(ws + 41943040);             //  8,388,608 B
    bf16_t* tmp    = (bf16_t*)(ws + 50331648);            //  8,388,608 B
    // total 58,720,256 B

    // q = bf16(query + query_pos)
    addcvt_k<<<4096, 256, 0, stream>>>(query, query_pos, q_bf16, NQ * CDIM);
    // v = bf16(value @ W_val + b_val)   (32768 x 256)
    gemm_k<true, true, false><<<dim3(4, 512), 256, 0, stream>>>(
        value, W_val, b_val, nullptr, v_bf16, NLVL * NQ, CDIM, CDIM);
    // off = q @ W_off + b_off           (16384 x 256) fp32
    gemm_k<false, false, false><<<dim3(4, 256), 256, 0, stream>>>(
        q_bf16, W_off, b_off, nullptr, c_off, NQ, CDIM, CDIM);
    // attn logits = q @ W_attn + b_attn (16384 x 128) fp32
    gemm_k<false, false, false><<<dim3(2, 256), 256, 0, stream>>>(
        q_bf16, W_attn, b_attn, nullptr, c_attn, NQ, 128, CDIM);
    // softmax over 16 per (q,h), in place
    softmax16_k<<<512, 256, 0, stream>>>(c_attn);
    // bilinear sampling + attention weighting -> tmp (16384 x 256) bf16
    sample_k<<<16384, 256, 0, stream>>>(v_bf16, c_off, c_attn, refp, tmp);
    // out = tmp @ W_out + b_out + query (identity)
    gemm_k<false, false, true><<<dim3(4, 256), 256, 0, stream>>>(
        tmp, W_out, b_out, query, out, NQ, CDIM, CDIM);
}

// Round 2
// 324.459 us; speedup vs baseline: 1.7605x; 1.7605x over previous
//
#include <hip/hip_runtime.h>
#include <hip/hip_bf16.h>
#include <math.h>

#define NQ     16384
#define CDIM   256
#define NHEADS 8
#define NPTS   8
#define NLVL   2
#define HH     128
#define WWID   128
#define DHEAD  32

typedef __bf16 bf16_t;
typedef __bf16 bf16x8 __attribute__((ext_vector_type(8)));
typedef __bf16 bf16x4 __attribute__((ext_vector_type(4)));
typedef float  f32x4  __attribute__((ext_vector_type(4)));

__device__ __forceinline__ bf16_t f2b(float f) { return (bf16_t)f; }

// ---------------------------------------------------------------------------
// q = bf16(query + query_pos), vectorized x4
// ---------------------------------------------------------------------------
__global__ __launch_bounds__(256) void addcvt_k(const float* __restrict__ a,
                                                const float* __restrict__ b,
                                                bf16_t* __restrict__ o, int n) {
    int i = (blockIdx.x * 256 + threadIdx.x) * 4;
    if (i >= n) return;
    float4 av = *reinterpret_cast<const float4*>(a + i);
    float4 bv = *reinterpret_cast<const float4*>(b + i);
    bf16x4 ov;
    ov[0] = f2b(av.x + bv.x);
    ov[1] = f2b(av.y + bv.y);
    ov[2] = f2b(av.z + bv.z);
    ov[3] = f2b(av.w + bv.w);
    *reinterpret_cast<bf16x4*>(o + i) = ov;
}

// ---------------------------------------------------------------------------
// GEMM: C[M,N] = A[M,K] * B[K,N] + bias (+ addsrc). A bf16 (or fp32->bf16 on
// stage), B fp32 (converted on stage), MFMA 16x16x32 bf16, 64x64 tile,
// 4 waves (wave w owns rows 16w..16w+15, 4 col tiles of 16).
// ---------------------------------------------------------------------------
template <bool A_F32, bool OUT_BF16, bool ADD_SRC>
__global__ __launch_bounds__(256) void gemm_k(const void* __restrict__ Aptr,
                                              const float* __restrict__ B,
                                              const float* __restrict__ bias,
                                              const float* __restrict__ addsrc,
                                              void* __restrict__ Cout,
                                              int M, int N, int K) {
    __shared__ __align__(16) bf16_t As[64][40];  // pad 32->40 (80B row stride)
    __shared__ __align__(16) bf16_t Bs[64][40];  // transposed: [n][k]

    const int tid  = threadIdx.x;
    const int wave = tid >> 6;
    const int lane = tid & 63;
    const int rowBase = blockIdx.y * 64;
    const int colBase = blockIdx.x * 64;

    // staging indices
    const int ar = tid >> 2;        // 0..63 (A row)
    const int ak = (tid & 3) * 8;   // 0,8,16,24 (A k chunk)
    const int bk = tid >> 3;        // 0..31 (B k row)
    const int bn = (tid & 7) * 8;   // 0..56 (B n chunk)

    f32x4 acc[4] = {{0.f, 0.f, 0.f, 0.f}, {0.f, 0.f, 0.f, 0.f},
                    {0.f, 0.f, 0.f, 0.f}, {0.f, 0.f, 0.f, 0.f}};

    const int fr = lane & 15;
    const int fq = lane >> 4;

    for (int k0 = 0; k0 < K; k0 += 32) {
        __syncthreads();
        // --- stage A tile (64 x 32) ---
        if (A_F32) {
            const float* ap = (const float*)Aptr + (size_t)(rowBase + ar) * K + k0 + ak;
            float4 a0 = *reinterpret_cast<const float4*>(ap);
            float4 a1 = *reinterpret_cast<const float4*>(ap + 4);
            bf16x8 av;
            av[0] = f2b(a0.x); av[1] = f2b(a0.y); av[2] = f2b(a0.z); av[3] = f2b(a0.w);
            av[4] = f2b(a1.x); av[5] = f2b(a1.y); av[6] = f2b(a1.z); av[7] = f2b(a1.w);
            *reinterpret_cast<bf16x8*>(&As[ar][ak]) = av;
        } else {
            const bf16_t* ap = (const bf16_t*)Aptr + (size_t)(rowBase + ar) * K + k0 + ak;
            *reinterpret_cast<uint4*>(&As[ar][ak]) = *reinterpret_cast<const uint4*>(ap);
        }
        // --- stage B tile (32 x 64) transposed into Bs[n][k] ---
        {
            const float* bp = B + (size_t)(k0 + bk) * N + colBase + bn;
            float4 b0 = *reinterpret_cast<const float4*>(bp);
            float4 b1 = *reinterpret_cast<const float4*>(bp + 4);
            Bs[bn + 0][bk] = f2b(b0.x);
            Bs[bn + 1][bk] = f2b(b0.y);
            Bs[bn + 2][bk] = f2b(b0.z);
            Bs[bn + 3][bk] = f2b(b0.w);
            Bs[bn + 4][bk] = f2b(b1.x);
            Bs[bn + 5][bk] = f2b(b1.y);
            Bs[bn + 6][bk] = f2b(b1.z);
            Bs[bn + 7][bk] = f2b(b1.w);
        }
        __syncthreads();
        // --- compute ---
        bf16x8 afrag = *reinterpret_cast<const bf16x8*>(&As[wave * 16 + fr][fq * 8]);
#pragma unroll
        for (int t = 0; t < 4; ++t) {
            bf16x8 bfrag = *reinterpret_cast<const bf16x8*>(&Bs[t * 16 + fr][fq * 8]);
            acc[t] = __builtin_amdgcn_mfma_f32_16x16x32_bf16(afrag, bfrag, acc[t], 0, 0, 0);
        }
    }

    // --- epilogue: D[row = quad*4+reg][col = lane&15] ---
#pragma unroll
    for (int t = 0; t < 4; ++t) {
        const int col = colBase + t * 16 + fr;
        const float bv = bias[col];
#pragma unroll
        for (int r = 0; r < 4; ++r) {
            const int row = rowBase + wave * 16 + fq * 4 + r;
            float vv = acc[t][r] + bv;
            if (ADD_SRC) vv += addsrc[(size_t)row * N + col];
            if (OUT_BF16)
                ((bf16_t*)Cout)[(size_t)row * N + col] = f2b(vv);
            else
                ((float*)Cout)[(size_t)row * N + col] = vv;
        }
    }
}

// ---------------------------------------------------------------------------
// in-place softmax over contiguous groups of 16 (NQ*HEADS groups)
// ---------------------------------------------------------------------------
__global__ __launch_bounds__(256) void softmax16_k(float* __restrict__ a) {
    int g = blockIdx.x * 256 + threadIdx.x;
    if (g >= NQ * NHEADS) return;
    float* p = a + (size_t)g * 16;
    float4 r0 = *reinterpret_cast<const float4*>(p);
    float4 r1 = *reinterpret_cast<const float4*>(p + 4);
    float4 r2 = *reinterpret_cast<const float4*>(p + 8);
    float4 r3 = *reinterpret_cast<const float4*>(p + 12);
    float e[16] = {r0.x, r0.y, r0.z, r0.w, r1.x, r1.y, r1.z, r1.w,
                   r2.x, r2.y, r2.z, r2.w, r3.x, r3.y, r3.z, r3.w};
    float m = e[0];
#pragma unroll
    for (int i = 1; i < 16; ++i) m = fmaxf(m, e[i]);
    float s = 0.f;
#pragma unroll
    for (int i = 0; i < 16; ++i) { e[i] = __expf(e[i] - m); s += e[i]; }
    float inv = 1.f / s;
#pragma unroll
    for (int i = 0; i < 16; ++i) e[i] *= inv;
    *reinterpret_cast<float4*>(p)      = make_float4(e[0], e[1], e[2], e[3]);
    *reinterpret_cast<float4*>(p + 4)  = make_float4(e[4], e[5], e[6], e[7]);
    *reinterpret_cast<float4*>(p + 8)  = make_float4(e[8], e[9], e[10], e[11]);
    *reinterpret_cast<float4*>(p + 12) = make_float4(e[12], e[13], e[14], e[15]);
}

// ---------------------------------------------------------------------------
// Bilinear sampling + attention-weighted accumulation.
// Block = 8 queries. Thread: qloc = tid>>5, h = (tid>>2)&7, chunk = tid&3.
// Each thread owns 8 contiguous dims -> bf16x8 (16 B) vector taps.
// ---------------------------------------------------------------------------
__device__ __forceinline__ void tap8(const bf16_t* __restrict__ base,
                                     int x, int y, float wgt, float* acc) {
    if (((unsigned)x < (unsigned)WWID) & ((unsigned)y < (unsigned)HH)) {
        bf16x8 vv = *reinterpret_cast<const bf16x8*>(base + (size_t)(y * WWID + x) * CDIM);
#pragma unroll
        for (int i = 0; i < 8; ++i) acc[i] = fmaf(wgt, (float)vv[i], acc[i]);
    }
}

__global__ __launch_bounds__(256) void sample_k(const bf16_t* __restrict__ v,
                                                const float* __restrict__ off,
                                                const float* __restrict__ attnw,
                                                const float* __restrict__ refp,
                                                bf16_t* __restrict__ tmp) {
    const int tid  = threadIdx.x;
    const int qloc = tid >> 5;
    const int h    = (tid >> 2) & 7;
    const int ck   = tid & 3;
    const int q    = blockIdx.x * 8 + qloc;

    float acc[8] = {0.f, 0.f, 0.f, 0.f, 0.f, 0.f, 0.f, 0.f};

#pragma unroll
    for (int l = 0; l < NLVL; ++l) {
        const float bx = refp[q * 4 + l * 2 + 0] * (float)WWID - 0.5f;
        const float by = refp[q * 4 + l * 2 + 1] * (float)HH - 0.5f;
        const bf16_t* base = v + (size_t)l * NQ * CDIM + h * DHEAD + ck * 8;
        const float* offp  = off + (size_t)q * CDIM + h * 32 + l * 16;
        const float* attp  = attnw + (size_t)q * 128 + h * 16 + l * 8;
#pragma unroll
        for (int p = 0; p < NPTS; ++p) {
            const float px = bx + offp[p * 2];
            const float py = by + offp[p * 2 + 1];
            const float w  = attp[p];
            const float x0f = floorf(px), y0f = floorf(py);
            const int x0 = (int)x0f, y0 = (int)y0f;
            const float wx1 = px - x0f, wy1 = py - y0f;
            const float wx0 = 1.f - wx1, wy0 = 1.f - wy1;
            tap8(base, x0,     y0,     w * wx0 * wy0, acc);
            tap8(base, x0 + 1, y0,     w * wx1 * wy0, acc);
            tap8(base, x0,     y0 + 1, w * wx0 * wy1, acc);
            tap8(base, x0 + 1, y0 + 1, w * wx1 * wy1, acc);
        }
    }

    bf16x8 ov;
#pragma unroll
    for (int i = 0; i < 8; ++i) ov[i] = f2b(acc[i]);
    *reinterpret_cast<bf16x8*>(tmp + (size_t)q * CDIM + h * DHEAD + ck * 8) = ov;
}

// ---------------------------------------------------------------------------
extern "C" void kernel_launch(void* const* d_in, const int* in_sizes, int n_in,
                              void* d_out, int out_size, void* d_ws, size_t ws_size,
                              hipStream_t stream) {
    const float* query     = (const float*)d_in[0];
    const float* query_pos = (const float*)d_in[1];
    const float* value     = (const float*)d_in[2];
    const float* refp      = (const float*)d_in[3];
    // d_in[4] spatial_shapes: static 128x128, hard-coded
    const float* W_off  = (const float*)d_in[5];
    const float* b_off  = (const float*)d_in[6];
    const float* W_attn = (const float*)d_in[7];
    const float* b_attn = (const float*)d_in[8];
    const float* W_val  = (const float*)d_in[9];
    const float* b_val  = (const float*)d_in[10];
    const float* W_out  = (const float*)d_in[11];
    const float* b_out  = (const float*)d_in[12];
    float* out = (float*)d_out;

    char* ws = (char*)d_ws;
    bf16_t* q_bf16 = (bf16_t*)(ws);                       //  8,388,608 B
    bf16_t* v_bf16 = (bf16_t*)(ws + 8388608);             // 16,777,216 B
    float*  c_off  = (float*)(ws + 25165824);             // 16,777,216 B
    float*  c_attn = (float*)(ws + 41943040);             //  8,388,608 B
    bf16_t* tmp    = (bf16_t*)(ws + 50331648);            //  8,388,608 B
    // total 58,720,256 B

    // q = bf16(query + query_pos)
    addcvt_k<<<4096, 256, 0, stream>>>(query, query_pos, q_bf16, NQ * CDIM);
    // v = bf16(value @ W_val + b_val)   (32768 x 256)
    gemm_k<true, true, false><<<dim3(4, 512), 256, 0, stream>>>(
        value, W_val, b_val, nullptr, v_bf16, NLVL * NQ, CDIM, CDIM);
    // off = q @ W_off + b_off           (16384 x 256) fp32
    gemm_k<false, false, false><<<dim3(4, 256), 256, 0, stream>>>(
        q_bf16, W_off, b_off, nullptr, c_off, NQ, CDIM, CDIM);
    // attn logits = q @ W_attn + b_attn (16384 x 128) fp32
    gemm_k<false, false, false><<<dim3(2, 256), 256, 0, stream>>>(
        q_bf16, W_attn, b_attn, nullptr, c_attn, NQ, 128, CDIM);
    // softmax over 16 per (q,h), in place
    softmax16_k<<<512, 256, 0, stream>>>(c_attn);
    // bilinear sampling + attention weighting -> tmp (16384 x 256) bf16
    sample_k<<<2048, 256, 0, stream>>>(v_bf16, c_off, c_attn, refp, tmp);
    // out = tmp @ W_out + b_out + query (identity)
    gemm_k<false, false, true><<<dim3(4, 256), 256, 0, stream>>>(
        tmp, W_out, b_out, query, out, NQ, CDIM, CDIM);
}

// Round 3
// 316.462 us; speedup vs baseline: 1.8050x; 1.0253x over previous
//
#include <hip/hip_runtime.h>
#include <hip/hip_bf16.h>
#include <math.h>

#define NQ     16384
#define CDIM   256
#define NHEADS 8
#define NPTS   8
#define NLVL   2
#define HH     128
#define WWID   128
#define DHEAD  32

typedef __bf16 bf16_t;
typedef __bf16 bf16x8 __attribute__((ext_vector_type(8)));
typedef __bf16 bf16x4 __attribute__((ext_vector_type(4)));
typedef float  f32x4  __attribute__((ext_vector_type(4)));

typedef __attribute__((address_space(1))) const uint32_t gau32;
typedef __attribute__((address_space(3))) uint32_t lau32;

__device__ __forceinline__ bf16_t f2b(float f) { return (bf16_t)f; }

// ---------------------------------------------------------------------------
// q = bf16(query + query_pos), vectorized x4
// ---------------------------------------------------------------------------
__global__ __launch_bounds__(256) void addcvt_k(const float* __restrict__ a,
                                                const float* __restrict__ b,
                                                bf16_t* __restrict__ o, int n) {
    int i = (blockIdx.x * 256 + threadIdx.x) * 4;
    if (i >= n) return;
    float4 av = *reinterpret_cast<const float4*>(a + i);
    float4 bv = *reinterpret_cast<const float4*>(b + i);
    bf16x4 ov;
    ov[0] = f2b(av.x + bv.x);
    ov[1] = f2b(av.y + bv.y);
    ov[2] = f2b(av.z + bv.z);
    ov[3] = f2b(av.w + bv.w);
    *reinterpret_cast<bf16x4*>(o + i) = ov;
}

// ---------------------------------------------------------------------------
// Wt[n][k] = bf16(W[k][n]);  K fixed = 256. Coalesced writes.
// ---------------------------------------------------------------------------
__global__ __launch_bounds__(256) void wtrans_k(const float* __restrict__ W,
                                                bf16_t* __restrict__ Wt, int N) {
    int i = blockIdx.x * 256 + threadIdx.x;   // i = n*256 + k
    int n = i >> 8;
    int k = i & 255;
    if (n >= N) return;
    Wt[i] = f2b(W[(size_t)k * N + n]);
}

// ---------------------------------------------------------------------------
// GEMM: C[M,N] = A[M,K] * Bt[N,K]^T + bias (+ addsrc).
// 128x128 tile, BK=64, 4 waves in 2x2, each wave 64x64 (4x4 accs of 16x16).
// A bf16 staged via global_load_lds width=16 (or fp32 via register convert),
// Bt bf16 staged via global_load_lds. LDS rows UNPADDED (required by
// global_load_lds wave-uniform-base + lane*16 deposit rule).
// ---------------------------------------------------------------------------
template <bool A_F32, bool OUT_BF16, bool ADD_SRC>
__global__ __launch_bounds__(256, 2) void gemm128_k(const void* __restrict__ Aptr,
                                                    const bf16_t* __restrict__ Bt,
                                                    const float* __restrict__ bias,
                                                    const float* __restrict__ addsrc,
                                                    void* __restrict__ Cout,
                                                    int M, int N, int K) {
    __shared__ __align__(16) bf16_t As[128][64];
    __shared__ __align__(16) bf16_t Bs[128][64];

    const int tid  = threadIdx.x;
    const int wave = tid >> 6;
    const int lane = tid & 63;
    const int rowBase = blockIdx.y * 128;
    const int colBase = blockIdx.x * 128;
    const int wm = (wave & 1) * 64;
    const int wn = (wave >> 1) * 64;
    const int fr = lane & 15;
    const int fq = lane >> 4;

    f32x4 acc[4][4] = {};

    // staging lane mapping: 8 rows x 8 k-octets per wave-issue
    const int lrow = lane >> 3;          // 0..7
    const int lcol = (lane & 7) * 8;     // 0..56

    for (int k0 = 0; k0 < K; k0 += 64) {
        __syncthreads();
        if (A_F32) {
            // register staging with fp32->bf16 convert: thread -> row tid>>1,
            // k-chunk (tid&1)*32
            const int r = tid >> 1, kc = (tid & 1) * 32;
            const float* ap = (const float*)Aptr + (size_t)(rowBase + r) * K + k0 + kc;
            bf16_t* dst = &As[r][kc];
#pragma unroll
            for (int u = 0; u < 4; ++u) {
                float4 f0 = *reinterpret_cast<const float4*>(ap + u * 8);
                float4 f1 = *reinterpret_cast<const float4*>(ap + u * 8 + 4);
                bf16x8 bv;
                bv[0] = f2b(f0.x); bv[1] = f2b(f0.y); bv[2] = f2b(f0.z); bv[3] = f2b(f0.w);
                bv[4] = f2b(f1.x); bv[5] = f2b(f1.y); bv[6] = f2b(f1.z); bv[7] = f2b(f1.w);
                *reinterpret_cast<bf16x8*>(dst + u * 8) = bv;
            }
        } else {
            const bf16_t* Abf = (const bf16_t*)Aptr;
#pragma unroll
            for (int t = 0; t < 4; ++t) {
                const bf16_t* src =
                    Abf + (size_t)(rowBase + wave * 32 + t * 8 + lrow) * K + k0 + lcol;
                __builtin_amdgcn_global_load_lds((gau32*)src,
                                                 (lau32*)&As[wave * 32 + t * 8][0],
                                                 16, 0, 0);
            }
        }
#pragma unroll
        for (int t = 0; t < 4; ++t) {
            const bf16_t* src =
                Bt + (size_t)(colBase + wave * 32 + t * 8 + lrow) * K + k0 + lcol;
            __builtin_amdgcn_global_load_lds((gau32*)src,
                                             (lau32*)&Bs[wave * 32 + t * 8][0],
                                             16, 0, 0);
        }
        __syncthreads();
#pragma unroll
        for (int ks = 0; ks < 2; ++ks) {
            bf16x8 af[4], bfr[4];
#pragma unroll
            for (int i = 0; i < 4; ++i)
                af[i] = *reinterpret_cast<const bf16x8*>(&As[wm + i * 16 + fr][ks * 32 + fq * 8]);
#pragma unroll
            for (int j = 0; j < 4; ++j)
                bfr[j] = *reinterpret_cast<const bf16x8*>(&Bs[wn + j * 16 + fr][ks * 32 + fq * 8]);
#pragma unroll
            for (int i = 0; i < 4; ++i)
#pragma unroll
                for (int j = 0; j < 4; ++j)
                    acc[i][j] = __builtin_amdgcn_mfma_f32_16x16x32_bf16(af[i], bfr[j],
                                                                        acc[i][j], 0, 0, 0);
        }
    }

    // epilogue: D[row = fq*4 + r][col = fr] per 16x16 tile
#pragma unroll
    for (int j = 0; j < 4; ++j) {
        const int col = colBase + wn + j * 16 + fr;
        const float bv = bias[col];
#pragma unroll
        for (int i = 0; i < 4; ++i) {
#pragma unroll
            for (int r = 0; r < 4; ++r) {
                const int row = rowBase + wm + i * 16 + fq * 4 + r;
                float vv = acc[i][j][r] + bv;
                if (ADD_SRC) vv += addsrc[(size_t)row * N + col];
                if (OUT_BF16)
                    ((bf16_t*)Cout)[(size_t)row * N + col] = f2b(vv);
                else
                    ((float*)Cout)[(size_t)row * N + col] = vv;
            }
        }
    }
}

// ---------------------------------------------------------------------------
// in-place softmax over contiguous groups of 16 (NQ*HEADS groups)
// ---------------------------------------------------------------------------
__global__ __launch_bounds__(256) void softmax16_k(float* __restrict__ a) {
    int g = blockIdx.x * 256 + threadIdx.x;
    if (g >= NQ * NHEADS) return;
    float* p = a + (size_t)g * 16;
    float4 r0 = *reinterpret_cast<const float4*>(p);
    float4 r1 = *reinterpret_cast<const float4*>(p + 4);
    float4 r2 = *reinterpret_cast<const float4*>(p + 8);
    float4 r3 = *reinterpret_cast<const float4*>(p + 12);
    float e[16] = {r0.x, r0.y, r0.z, r0.w, r1.x, r1.y, r1.z, r1.w,
                   r2.x, r2.y, r2.z, r2.w, r3.x, r3.y, r3.z, r3.w};
    float m = e[0];
#pragma unroll
    for (int i = 1; i < 16; ++i) m = fmaxf(m, e[i]);
    float s = 0.f;
#pragma unroll
    for (int i = 0; i < 16; ++i) { e[i] = __expf(e[i] - m); s += e[i]; }
    float inv = 1.f / s;
#pragma unroll
    for (int i = 0; i < 16; ++i) e[i] *= inv;
    *reinterpret_cast<float4*>(p)      = make_float4(e[0], e[1], e[2], e[3]);
    *reinterpret_cast<float4*>(p + 4)  = make_float4(e[4], e[5], e[6], e[7]);
    *reinterpret_cast<float4*>(p + 8)  = make_float4(e[8], e[9], e[10], e[11]);
    *reinterpret_cast<float4*>(p + 12) = make_float4(e[12], e[13], e[14], e[15]);
}

// ---------------------------------------------------------------------------
// Bilinear sampling + attention-weighted accumulation.
// Block = 8 queries. Thread: qloc = tid>>5, h = (tid>>2)&7, chunk = tid&3.
// Each thread owns 8 contiguous dims -> bf16x8 (16 B) vector taps.
// ---------------------------------------------------------------------------
__device__ __forceinline__ void tap8(const bf16_t* __restrict__ base,
                                     int x, int y, float wgt, float* acc) {
    if (((unsigned)x < (unsigned)WWID) & ((unsigned)y < (unsigned)HH)) {
        bf16x8 vv = *reinterpret_cast<const bf16x8*>(base + (size_t)(y * WWID + x) * CDIM);
#pragma unroll
        for (int i = 0; i < 8; ++i) acc[i] = fmaf(wgt, (float)vv[i], acc[i]);
    }
}

__global__ __launch_bounds__(256) void sample_k(const bf16_t* __restrict__ v,
                                                const float* __restrict__ off,
                                                const float* __restrict__ attnw,
                                                const float* __restrict__ refp,
                                                bf16_t* __restrict__ tmp) {
    const int tid  = threadIdx.x;
    const int qloc = tid >> 5;
    const int h    = (tid >> 2) & 7;
    const int ck   = tid & 3;
    const int q    = blockIdx.x * 8 + qloc;

    float acc[8] = {0.f, 0.f, 0.f, 0.f, 0.f, 0.f, 0.f, 0.f};

#pragma unroll
    for (int l = 0; l < NLVL; ++l) {
        const float bx = refp[q * 4 + l * 2 + 0] * (float)WWID - 0.5f;
        const float by = refp[q * 4 + l * 2 + 1] * (float)HH - 0.5f;
        const bf16_t* base = v + (size_t)l * NQ * CDIM + h * DHEAD + ck * 8;
        const float* offp  = off + (size_t)q * CDIM + h * 32 + l * 16;
        const float* attp  = attnw + (size_t)q * 128 + h * 16 + l * 8;
#pragma unroll
        for (int p = 0; p < NPTS; ++p) {
            const float px = bx + offp[p * 2];
            const float py = by + offp[p * 2 + 1];
            const float w  = attp[p];
            const float x0f = floorf(px), y0f = floorf(py);
            const int x0 = (int)x0f, y0 = (int)y0f;
            const float wx1 = px - x0f, wy1 = py - y0f;
            const float wx0 = 1.f - wx1, wy0 = 1.f - wy1;
            tap8(base, x0,     y0,     w * wx0 * wy0, acc);
            tap8(base, x0 + 1, y0,     w * wx1 * wy0, acc);
            tap8(base, x0,     y0 + 1, w * wx0 * wy1, acc);
            tap8(base, x0 + 1, y0 + 1, w * wx1 * wy1, acc);
        }
    }

    bf16x8 ov;
#pragma unroll
    for (int i = 0; i < 8; ++i) ov[i] = f2b(acc[i]);
    *reinterpret_cast<bf16x8*>(tmp + (size_t)q * CDIM + h * DHEAD + ck * 8) = ov;
}

// ---------------------------------------------------------------------------
extern "C" void kernel_launch(void* const* d_in, const int* in_sizes, int n_in,
                              void* d_out, int out_size, void* d_ws, size_t ws_size,
                              hipStream_t stream) {
    const float* query     = (const float*)d_in[0];
    const float* query_pos = (const float*)d_in[1];
    const float* value     = (const float*)d_in[2];
    const float* refp      = (const float*)d_in[3];
    // d_in[4] spatial_shapes: static 128x128, hard-coded
    const float* W_off  = (const float*)d_in[5];
    const float* b_off  = (const float*)d_in[6];
    const float* W_attn = (const float*)d_in[7];
    const float* b_attn = (const float*)d_in[8];
    const float* W_val  = (const float*)d_in[9];
    const float* b_val  = (const float*)d_in[10];
    const float* W_out  = (const float*)d_in[11];
    const float* b_out  = (const float*)d_in[12];
    float* out = (float*)d_out;

    char* ws = (char*)d_ws;
    bf16_t* q_bf16 = (bf16_t*)(ws);                       //  8,388,608 B
    bf16_t* v_bf16 = (bf16_t*)(ws + 8388608);             // 16,777,216 B
    float*  c_off  = (float*)(ws + 25165824);             // 16,777,216 B
    float*  c_attn = (float*)(ws + 41943040);             //  8,388,608 B
    bf16_t* tmp    = (bf16_t*)(ws + 50331648);            //  8,388,608 B
    bf16_t* Wt_val  = (bf16_t*)(ws + 58720256);           //    131,072 B
    bf16_t* Wt_off  = (bf16_t*)(ws + 58851328);           //    131,072 B
    bf16_t* Wt_attn = (bf16_t*)(ws + 58982400);           //     65,536 B
    bf16_t* Wt_out  = (bf16_t*)(ws + 59047936);           //    131,072 B
    // total 59,179,008 B

    // transpose+convert weights to bf16 [N][K]
    wtrans_k<<<256, 256, 0, stream>>>(W_val,  Wt_val,  256);
    wtrans_k<<<256, 256, 0, stream>>>(W_off,  Wt_off,  256);
    wtrans_k<<<128, 256, 0, stream>>>(W_attn, Wt_attn, 128);
    wtrans_k<<<256, 256, 0, stream>>>(W_out,  Wt_out,  256);

    // q = bf16(query + query_pos)
    addcvt_k<<<4096, 256, 0, stream>>>(query, query_pos, q_bf16, NQ * CDIM);
    // v = bf16(value @ W_val + b_val)   (32768 x 256), fp32 A
    gemm128_k<true, true, false><<<dim3(2, 256), 256, 0, stream>>>(
        value, Wt_val, b_val, nullptr, v_bf16, NLVL * NQ, CDIM, CDIM);
    // off = q @ W_off + b_off           (16384 x 256) fp32 out
    gemm128_k<false, false, false><<<dim3(2, 128), 256, 0, stream>>>(
        q_bf16, Wt_off, b_off, nullptr, c_off, NQ, CDIM, CDIM);
    // attn logits = q @ W_attn + b_attn (16384 x 128) fp32 out
    gemm128_k<false, false, false><<<dim3(1, 128), 256, 0, stream>>>(
        q_bf16, Wt_attn, b_attn, nullptr, c_attn, NQ, 128, CDIM);
    // softmax over 16 per (q,h), in place
    softmax16_k<<<512, 256, 0, stream>>>(c_attn);
    // bilinear sampling + attention weighting -> tmp (16384 x 256) bf16
    sample_k<<<2048, 256, 0, stream>>>(v_bf16, c_off, c_attn, refp, tmp);
    // out = tmp @ W_out + b_out + query (identity)
    gemm128_k<false, false, true><<<dim3(2, 128), 256, 0, stream>>>(
        tmp, Wt_out, b_out, query, out, NQ, CDIM, CDIM);
}

// Round 4
// 241.128 us; speedup vs baseline: 2.3690x; 1.3124x over previous
//
#include <hip/hip_runtime.h>
#include <hip/hip_bf16.h>
#include <math.h>

#define NQ     16384
#define CDIM   256
#define NHEADS 8
#define NPTS   8
#define NLVL   2
#define HH     128
#define WWID   128
#define DHEAD  32
#define NCAT   384   // fused off(256) + attn(128) projection width

typedef __bf16 bf16_t;
typedef __bf16 bf16x8 __attribute__((ext_vector_type(8)));
typedef float  f32x4  __attribute__((ext_vector_type(4)));

typedef __attribute__((address_space(1))) const uint32_t gau32;
typedef __attribute__((address_space(3))) uint32_t lau32;

__device__ __forceinline__ bf16_t f2b(float f) { return (bf16_t)f; }

// ---------------------------------------------------------------------------
// Wt[n][k] = bf16(W[k][n]);  K fixed = 256.
// ---------------------------------------------------------------------------
__global__ __launch_bounds__(256) void wtrans_k(const float* __restrict__ W,
                                                bf16_t* __restrict__ Wt, int N) {
    int i = blockIdx.x * 256 + threadIdx.x;   // i = n*256 + k
    int n = i >> 8;
    int k = i & 255;
    if (n >= N) return;
    Wt[i] = f2b(W[(size_t)k * N + n]);
}

// ---------------------------------------------------------------------------
// GEMM: C[M,N] = A[M,K] * Bt[N,K]^T + bias (+ addsrc).
// 128x128 tile, BK=64, 4 waves 2x2, each wave 64x64 (4x4 accs of 16x16).
// A_MODE: 0 = bf16 A (global_load_lds), 1 = fp32 A (register convert),
//         2 = fp32 A + fp32 A2 summed (register convert).
// PERM_V: epilogue scatters to per-head layout (l,h,cell,dh) for the v-proj.
// ---------------------------------------------------------------------------
template <int A_MODE, bool OUT_BF16, bool ADD_SRC, bool PERM_V>
__global__ __launch_bounds__(256, 2) void gemm128_k(const void* __restrict__ Aptr,
                                                    const void* __restrict__ Aptr2,
                                                    const bf16_t* __restrict__ Bt,
                                                    const float* __restrict__ bias,
                                                    const float* __restrict__ bias2,
                                                    int Nsplit,
                                                    const float* __restrict__ addsrc,
                                                    void* __restrict__ Cout,
                                                    int M, int N, int K) {
    __shared__ __align__(16) bf16_t As[128][64];
    __shared__ __align__(16) bf16_t Bs[128][64];

    const int tid  = threadIdx.x;
    const int wave = tid >> 6;
    const int lane = tid & 63;
    const int rowBase = blockIdx.y * 128;
    const int colBase = blockIdx.x * 128;
    const int wm = (wave & 1) * 64;
    const int wn = (wave >> 1) * 64;
    const int fr = lane & 15;
    const int fq = lane >> 4;

    f32x4 acc[4][4] = {};

    const int lrow = lane >> 3;          // 0..7
    const int lcol = (lane & 7) * 8;     // 0..56

    for (int k0 = 0; k0 < K; k0 += 64) {
        __syncthreads();
        if (A_MODE != 0) {
            const int r = tid >> 1, kc = (tid & 1) * 32;
            const float* ap = (const float*)Aptr + (size_t)(rowBase + r) * K + k0 + kc;
            const float* ap2 = (A_MODE == 2)
                ? (const float*)Aptr2 + (size_t)(rowBase + r) * K + k0 + kc : nullptr;
            bf16_t* dst = &As[r][kc];
#pragma unroll
            for (int u = 0; u < 4; ++u) {
                float4 f0 = *reinterpret_cast<const float4*>(ap + u * 8);
                float4 f1 = *reinterpret_cast<const float4*>(ap + u * 8 + 4);
                if (A_MODE == 2) {
                    float4 g0 = *reinterpret_cast<const float4*>(ap2 + u * 8);
                    float4 g1 = *reinterpret_cast<const float4*>(ap2 + u * 8 + 4);
                    f0.x += g0.x; f0.y += g0.y; f0.z += g0.z; f0.w += g0.w;
                    f1.x += g1.x; f1.y += g1.y; f1.z += g1.z; f1.w += g1.w;
                }
                bf16x8 bv;
                bv[0] = f2b(f0.x); bv[1] = f2b(f0.y); bv[2] = f2b(f0.z); bv[3] = f2b(f0.w);
                bv[4] = f2b(f1.x); bv[5] = f2b(f1.y); bv[6] = f2b(f1.z); bv[7] = f2b(f1.w);
                *reinterpret_cast<bf16x8*>(dst + u * 8) = bv;
            }
        } else {
            const bf16_t* Abf = (const bf16_t*)Aptr;
#pragma unroll
            for (int t = 0; t < 4; ++t) {
                const bf16_t* src =
                    Abf + (size_t)(rowBase + wave * 32 + t * 8 + lrow) * K + k0 + lcol;
                __builtin_amdgcn_global_load_lds((gau32*)src,
                                                 (lau32*)&As[wave * 32 + t * 8][0],
                                                 16, 0, 0);
            }
        }
#pragma unroll
        for (int t = 0; t < 4; ++t) {
            const bf16_t* src =
                Bt + (size_t)(colBase + wave * 32 + t * 8 + lrow) * K + k0 + lcol;
            __builtin_amdgcn_global_load_lds((gau32*)src,
                                             (lau32*)&Bs[wave * 32 + t * 8][0],
                                             16, 0, 0);
        }
        __syncthreads();
#pragma unroll
        for (int ks = 0; ks < 2; ++ks) {
            bf16x8 af[4], bfr[4];
#pragma unroll
            for (int i = 0; i < 4; ++i)
                af[i] = *reinterpret_cast<const bf16x8*>(&As[wm + i * 16 + fr][ks * 32 + fq * 8]);
#pragma unroll
            for (int j = 0; j < 4; ++j)
                bfr[j] = *reinterpret_cast<const bf16x8*>(&Bs[wn + j * 16 + fr][ks * 32 + fq * 8]);
#pragma unroll
            for (int i = 0; i < 4; ++i)
#pragma unroll
                for (int j = 0; j < 4; ++j)
                    acc[i][j] = __builtin_amdgcn_mfma_f32_16x16x32_bf16(af[i], bfr[j],
                                                                        acc[i][j], 0, 0, 0);
        }
    }

    // epilogue: D[row = fq*4 + r][col = fr] per 16x16 tile
#pragma unroll
    for (int j = 0; j < 4; ++j) {
        const int col = colBase + wn + j * 16 + fr;
        const float bv = (col < Nsplit) ? bias[col] : bias2[col - Nsplit];
#pragma unroll
        for (int i = 0; i < 4; ++i) {
#pragma unroll
            for (int r = 0; r < 4; ++r) {
                const int row = rowBase + wm + i * 16 + fq * 4 + r;
                float vv = acc[i][j][r] + bv;
                if (ADD_SRC) vv += addsrc[(size_t)row * N + col];
                if (PERM_V) {
                    // row = l*16384 + cell, col = h*32 + dh
                    const int l = row >> 14, cell = row & 16383;
                    const size_t dst =
                        (((size_t)(l * NHEADS + (col >> 5)) * NQ + cell) << 5) + (col & 31);
                    ((bf16_t*)Cout)[dst] = f2b(vv);
                } else if (OUT_BF16) {
                    ((bf16_t*)Cout)[(size_t)row * N + col] = f2b(vv);
                } else {
                    ((float*)Cout)[(size_t)row * N + col] = vv;
                }
            }
        }
    }
}

// ---------------------------------------------------------------------------
// in-place softmax over the attn section of cbuf (cols 256..383, stride 384)
// ---------------------------------------------------------------------------
__global__ __launch_bounds__(256) void softmax16_k(float* __restrict__ cbuf) {
    int g = blockIdx.x * 256 + threadIdx.x;  // (q,h) group
    if (g >= NQ * NHEADS) return;
    float* p = cbuf + (size_t)(g >> 3) * NCAT + 256 + (g & 7) * 16;
    float4 r0 = *reinterpret_cast<const float4*>(p);
    float4 r1 = *reinterpret_cast<const float4*>(p + 4);
    float4 r2 = *reinterpret_cast<const float4*>(p + 8);
    float4 r3 = *reinterpret_cast<const float4*>(p + 12);
    float e[16] = {r0.x, r0.y, r0.z, r0.w, r1.x, r1.y, r1.z, r1.w,
                   r2.x, r2.y, r2.z, r2.w, r3.x, r3.y, r3.z, r3.w};
    float m = e[0];
#pragma unroll
    for (int i = 1; i < 16; ++i) m = fmaxf(m, e[i]);
    float s = 0.f;
#pragma unroll
    for (int i = 0; i < 16; ++i) { e[i] = __expf(e[i] - m); s += e[i]; }
    float inv = 1.f / s;
#pragma unroll
    for (int i = 0; i < 16; ++i) e[i] *= inv;
    *reinterpret_cast<float4*>(p)      = make_float4(e[0], e[1], e[2], e[3]);
    *reinterpret_cast<float4*>(p + 4)  = make_float4(e[4], e[5], e[6], e[7]);
    *reinterpret_cast<float4*>(p + 8)  = make_float4(e[8], e[9], e[10], e[11]);
    *reinterpret_cast<float4*>(p + 12) = make_float4(e[12], e[13], e[14], e[15]);
}

// ---------------------------------------------------------------------------
// Bilinear sampling, head-partitioned for XCD-L2 locality.
// v2 layout: (l, h, y, x, 32dh) -> per-head slice is 2 MB (fits 4 MB XCD L2).
// head = blockIdx % 8 (round-robin block->XCD => one head per XCD).
// Block: 256 threads = 64 queries x 4 dim-chunks of 8.
// ---------------------------------------------------------------------------
__device__ __forceinline__ void tap8(const bf16_t* __restrict__ base,
                                     int x, int y, float wgt, float* acc) {
    if (((unsigned)x < (unsigned)WWID) & ((unsigned)y < (unsigned)HH)) {
        bf16x8 vv = *reinterpret_cast<const bf16x8*>(base + (size_t)(y * WWID + x) * DHEAD);
#pragma unroll
        for (int i = 0; i < 8; ++i) acc[i] = fmaf(wgt, (float)vv[i], acc[i]);
    }
}

__global__ __launch_bounds__(256) void sample_k(const bf16_t* __restrict__ v2,
                                                const float* __restrict__ cbuf,
                                                const float* __restrict__ refp,
                                                bf16_t* __restrict__ tmp) {
    const int b    = blockIdx.x;
    const int h    = b & 7;          // head -> XCD (round-robin dispatch)
    const int qblk = b >> 3;
    const int tid  = threadIdx.x;
    const int qloc = tid >> 2;
    const int ck   = tid & 3;
    const int q    = qblk * 64 + qloc;

    float acc[8] = {0.f, 0.f, 0.f, 0.f, 0.f, 0.f, 0.f, 0.f};

    const float4 rp = *reinterpret_cast<const float4*>(refp + (size_t)q * 4);
    const float* qrow = cbuf + (size_t)q * NCAT;

#pragma unroll
    for (int l = 0; l < NLVL; ++l) {
        const float bx = (l == 0 ? rp.x : rp.z) * (float)WWID - 0.5f;
        const float by = (l == 0 ? rp.y : rp.w) * (float)HH - 0.5f;
        const bf16_t* base = v2 + ((size_t)(l * NHEADS + h) * NQ) * DHEAD + ck * 8;
        const float* offp  = qrow + h * 32 + l * 16;
        const float* attp  = qrow + 256 + h * 16 + l * 8;

        float4 o0 = *reinterpret_cast<const float4*>(offp);
        float4 o1 = *reinterpret_cast<const float4*>(offp + 4);
        float4 o2 = *reinterpret_cast<const float4*>(offp + 8);
        float4 o3 = *reinterpret_cast<const float4*>(offp + 12);
        float4 a0 = *reinterpret_cast<const float4*>(attp);
        float4 a1 = *reinterpret_cast<const float4*>(attp + 4);
        const float ox[8] = {o0.x, o0.z, o1.x, o1.z, o2.x, o2.z, o3.x, o3.z};
        const float oy[8] = {o0.y, o0.w, o1.y, o1.w, o2.y, o2.w, o3.y, o3.w};
        const float aw[8] = {a0.x, a0.y, a0.z, a0.w, a1.x, a1.y, a1.z, a1.w};

#pragma unroll
        for (int p = 0; p < NPTS; ++p) {
            const float px = bx + ox[p];
            const float py = by + oy[p];
            const float w  = aw[p];
            const float x0f = floorf(px), y0f = floorf(py);
            const int x0 = (int)x0f, y0 = (int)y0f;
            const float wx1 = px - x0f, wy1 = py - y0f;
            const float wx0 = 1.f - wx1, wy0 = 1.f - wy1;
            tap8(base, x0,     y0,     w * wx0 * wy0, acc);
            tap8(base, x0 + 1, y0,     w * wx1 * wy0, acc);
            tap8(base, x0,     y0 + 1, w * wx0 * wy1, acc);
            tap8(base, x0 + 1, y0 + 1, w * wx1 * wy1, acc);
        }
    }

    bf16x8 ov;
#pragma unroll
    for (int i = 0; i < 8; ++i) ov[i] = f2b(acc[i]);
    *reinterpret_cast<bf16x8*>(tmp + (size_t)q * CDIM + h * DHEAD + ck * 8) = ov;
}

// ---------------------------------------------------------------------------
extern "C" void kernel_launch(void* const* d_in, const int* in_sizes, int n_in,
                              void* d_out, int out_size, void* d_ws, size_t ws_size,
                              hipStream_t stream) {
    const float* query     = (const float*)d_in[0];
    const float* query_pos = (const float*)d_in[1];
    const float* value     = (const float*)d_in[2];
    const float* refp      = (const float*)d_in[3];
    // d_in[4] spatial_shapes: static 128x128, hard-coded
    const float* W_off  = (const float*)d_in[5];
    const float* b_off  = (const float*)d_in[6];
    const float* W_attn = (const float*)d_in[7];
    const float* b_attn = (const float*)d_in[8];
    const float* W_val  = (const float*)d_in[9];
    const float* b_val  = (const float*)d_in[10];
    const float* W_out  = (const float*)d_in[11];
    const float* b_out  = (const float*)d_in[12];
    float* out = (float*)d_out;

    char* ws = (char*)d_ws;
    bf16_t* v2      = (bf16_t*)(ws);                      // 16,777,216 B
    float*  cbuf    = (float*)(ws + 16777216);            // 25,165,824 B (16384x384 f32)
    bf16_t* tmp     = (bf16_t*)(ws + 41943040);           //  8,388,608 B
    bf16_t* Wt_val  = (bf16_t*)(ws + 50331648);           //    131,072 B
    bf16_t* Wt_qa   = (bf16_t*)(ws + 50462720);           //    196,608 B (384x256)
    bf16_t* Wt_out  = (bf16_t*)(ws + 50659328);           //    131,072 B
    // total 50,790,400 B

    // transpose+convert weights to bf16 [N][K]
    wtrans_k<<<256, 256, 0, stream>>>(W_val,  Wt_val, 256);
    wtrans_k<<<256, 256, 0, stream>>>(W_off,  Wt_qa, 256);
    wtrans_k<<<128, 256, 0, stream>>>(W_attn, Wt_qa + 256 * 256, 128);
    wtrans_k<<<256, 256, 0, stream>>>(W_out,  Wt_out, 256);

    // v2 = per-head-layout bf16(value @ W_val + b_val)
    gemm128_k<1, true, false, true><<<dim3(2, 256), 256, 0, stream>>>(
        value, nullptr, Wt_val, b_val, b_val, 256, nullptr, v2,
        NLVL * NQ, CDIM, CDIM);
    // cbuf = (query+query_pos) @ [W_off|W_attn] + [b_off|b_attn]  (16384 x 384)
    gemm128_k<2, false, false, false><<<dim3(3, 128), 256, 0, stream>>>(
        query, query_pos, Wt_qa, b_off, b_attn, 256, nullptr, cbuf,
        NQ, NCAT, CDIM);
    // softmax over 16 per (q,h), in place on attn section
    softmax16_k<<<512, 256, 0, stream>>>(cbuf);
    // bilinear sampling + attention weighting -> tmp (16384 x 256) bf16
    sample_k<<<2048, 256, 0, stream>>>(v2, cbuf, refp, tmp);
    // out = tmp @ W_out + b_out + query (identity)
    gemm128_k<0, false, true, false><<<dim3(2, 128), 256, 0, stream>>>(
        tmp, nullptr, Wt_out, b_out, b_out, 256, query, out,
        NQ, CDIM, CDIM);
}

// Round 5
// 216.815 us; speedup vs baseline: 2.6346x; 1.1121x over previous
//
#include <hip/hip_runtime.h>
#include <hip/hip_bf16.h>
#include <math.h>

#define NQ     16384
#define CDIM   256
#define NHEADS 8
#define NPTS   8
#define NLVL   2
#define HH     128
#define WWID   128
#define DHEAD  32
#define NCAT   384   // fused off(256) + attn(128) projection width

typedef __bf16 bf16_t;
typedef __bf16 bf16x8 __attribute__((ext_vector_type(8)));
typedef float  f32x4  __attribute__((ext_vector_type(4)));

typedef __attribute__((address_space(1))) const uint32_t gau32;
typedef __attribute__((address_space(3))) uint32_t lau32;

__device__ __forceinline__ bf16_t f2b(float f) { return (bf16_t)f; }

// ---------------------------------------------------------------------------
// All four weight transposes in ONE dispatch. Wt[n][k] = bf16(W[k][n]), K=256.
// blocks 0..255: W_val -> Wt_val | 256..511: W_off -> Wt_qa[0:256]
// 512..639: W_attn -> Wt_qa[256:384] | 640..895: W_out -> Wt_out
// ---------------------------------------------------------------------------
__global__ __launch_bounds__(256) void wtrans_all_k(const float* __restrict__ W_val,
                                                    const float* __restrict__ W_off,
                                                    const float* __restrict__ W_attn,
                                                    const float* __restrict__ W_out,
                                                    bf16_t* __restrict__ Wt_val,
                                                    bf16_t* __restrict__ Wt_qa,
                                                    bf16_t* __restrict__ Wt_out) {
    const int b = blockIdx.x;
    const float* W; bf16_t* Wt; int N, base;
    if (b < 256)      { W = W_val;  Wt = Wt_val;            N = 256; base = 0;   }
    else if (b < 512) { W = W_off;  Wt = Wt_qa;             N = 256; base = 256; }
    else if (b < 640) { W = W_attn; Wt = Wt_qa + 256 * 256; N = 128; base = 512; }
    else              { W = W_out;  Wt = Wt_out;            N = 256; base = 640; }
    int i = (b - base) * 256 + threadIdx.x;   // i = n*256 + k
    int n = i >> 8, k = i & 255;
    if (n >= N) return;
    Wt[i] = f2b(W[(size_t)k * N + n]);
}

// ---------------------------------------------------------------------------
// GEMM body: C[M,N] = A[M,K] * Bt[N,K]^T + bias (+ addsrc).
// 128x128 tile, BK=64, 4 waves 2x2, each wave 64x64 (4x4 accs of 16x16).
// A_MODE: 0 = bf16 A (global_load_lds), 1 = fp32 A (register convert),
//         2 = fp32 A + fp32 A2 summed.
// PERM_V: epilogue scatters to per-head layout (l,h,cell,dh).
// ---------------------------------------------------------------------------
template <int A_MODE, bool OUT_BF16, bool ADD_SRC, bool PERM_V>
__device__ __forceinline__ void gemm_body(bf16_t (&As)[128][64], bf16_t (&Bs)[128][64],
                                          int bidx, int bidy,
                                          const void* __restrict__ Aptr,
                                          const void* __restrict__ Aptr2,
                                          const bf16_t* __restrict__ Bt,
                                          const float* __restrict__ bias,
                                          const float* __restrict__ bias2,
                                          int Nsplit,
                                          const float* __restrict__ addsrc,
                                          void* __restrict__ Cout,
                                          int N, int K) {
    const int tid  = threadIdx.x;
    const int wave = tid >> 6;
    const int lane = tid & 63;
    const int rowBase = bidy * 128;
    const int colBase = bidx * 128;
    const int wm = (wave & 1) * 64;
    const int wn = (wave >> 1) * 64;
    const int fr = lane & 15;
    const int fq = lane >> 4;

    f32x4 acc[4][4] = {};

    const int lrow = lane >> 3;          // 0..7
    const int lcol = (lane & 7) * 8;     // 0..56

    for (int k0 = 0; k0 < K; k0 += 64) {
        __syncthreads();
        if (A_MODE != 0) {
            const int r = tid >> 1, kc = (tid & 1) * 32;
            const float* ap = (const float*)Aptr + (size_t)(rowBase + r) * K + k0 + kc;
            const float* ap2 = (A_MODE == 2)
                ? (const float*)Aptr2 + (size_t)(rowBase + r) * K + k0 + kc : nullptr;
            bf16_t* dst = &As[r][kc];
#pragma unroll
            for (int u = 0; u < 4; ++u) {
                float4 f0 = *reinterpret_cast<const float4*>(ap + u * 8);
                float4 f1 = *reinterpret_cast<const float4*>(ap + u * 8 + 4);
                if (A_MODE == 2) {
                    float4 g0 = *reinterpret_cast<const float4*>(ap2 + u * 8);
                    float4 g1 = *reinterpret_cast<const float4*>(ap2 + u * 8 + 4);
                    f0.x += g0.x; f0.y += g0.y; f0.z += g0.z; f0.w += g0.w;
                    f1.x += g1.x; f1.y += g1.y; f1.z += g1.z; f1.w += g1.w;
                }
                bf16x8 bv;
                bv[0] = f2b(f0.x); bv[1] = f2b(f0.y); bv[2] = f2b(f0.z); bv[3] = f2b(f0.w);
                bv[4] = f2b(f1.x); bv[5] = f2b(f1.y); bv[6] = f2b(f1.z); bv[7] = f2b(f1.w);
                *reinterpret_cast<bf16x8*>(dst + u * 8) = bv;
            }
        } else {
            const bf16_t* Abf = (const bf16_t*)Aptr;
#pragma unroll
            for (int t = 0; t < 4; ++t) {
                const bf16_t* src =
                    Abf + (size_t)(rowBase + wave * 32 + t * 8 + lrow) * K + k0 + lcol;
                __builtin_amdgcn_global_load_lds((gau32*)src,
                                                 (lau32*)&As[wave * 32 + t * 8][0],
                                                 16, 0, 0);
            }
        }
#pragma unroll
        for (int t = 0; t < 4; ++t) {
            const bf16_t* src =
                Bt + (size_t)(colBase + wave * 32 + t * 8 + lrow) * K + k0 + lcol;
            __builtin_amdgcn_global_load_lds((gau32*)src,
                                             (lau32*)&Bs[wave * 32 + t * 8][0],
                                             16, 0, 0);
        }
        __syncthreads();
#pragma unroll
        for (int ks = 0; ks < 2; ++ks) {
            bf16x8 af[4], bfr[4];
#pragma unroll
            for (int i = 0; i < 4; ++i)
                af[i] = *reinterpret_cast<const bf16x8*>(&As[wm + i * 16 + fr][ks * 32 + fq * 8]);
#pragma unroll
            for (int j = 0; j < 4; ++j)
                bfr[j] = *reinterpret_cast<const bf16x8*>(&Bs[wn + j * 16 + fr][ks * 32 + fq * 8]);
#pragma unroll
            for (int i = 0; i < 4; ++i)
#pragma unroll
                for (int j = 0; j < 4; ++j)
                    acc[i][j] = __builtin_amdgcn_mfma_f32_16x16x32_bf16(af[i], bfr[j],
                                                                        acc[i][j], 0, 0, 0);
        }
    }

    // epilogue: D[row = fq*4 + r][col = fr] per 16x16 tile
#pragma unroll
    for (int j = 0; j < 4; ++j) {
        const int col = colBase + wn + j * 16 + fr;
        const float bv = (col < Nsplit) ? bias[col] : bias2[col - Nsplit];
#pragma unroll
        for (int i = 0; i < 4; ++i) {
#pragma unroll
            for (int r = 0; r < 4; ++r) {
                const int row = rowBase + wm + i * 16 + fq * 4 + r;
                float vv = acc[i][j][r] + bv;
                if (ADD_SRC) vv += addsrc[(size_t)row * N + col];
                if (PERM_V) {
                    const int l = row >> 14, cell = row & 16383;
                    const size_t dst =
                        (((size_t)(l * NHEADS + (col >> 5)) * NQ + cell) << 5) + (col & 31);
                    ((bf16_t*)Cout)[dst] = f2b(vv);
                } else if (OUT_BF16) {
                    ((bf16_t*)Cout)[(size_t)row * N + col] = f2b(vv);
                } else {
                    ((float*)Cout)[(size_t)row * N + col] = vv;
                }
            }
        }
    }
}

// ---------------------------------------------------------------------------
// Fused projections: blocks 0..511 = v-proj (fp32 value -> per-head bf16 v2),
// blocks 512..895 = (query+query_pos) @ [W_off|W_attn] -> cbuf fp32.
// ---------------------------------------------------------------------------
__global__ __launch_bounds__(256, 3) void fused_proj_k(const float* __restrict__ value,
                                                       const float* __restrict__ query,
                                                       const float* __restrict__ query_pos,
                                                       const bf16_t* __restrict__ Wt_val,
                                                       const bf16_t* __restrict__ Wt_qa,
                                                       const float* __restrict__ b_val,
                                                       const float* __restrict__ b_off,
                                                       const float* __restrict__ b_attn,
                                                       bf16_t* __restrict__ v2,
                                                       float* __restrict__ cbuf) {
    __shared__ __align__(16) bf16_t As[128][64];
    __shared__ __align__(16) bf16_t Bs[128][64];
    const int b = blockIdx.x;
    if (b < 512) {
        gemm_body<1, true, false, true>(As, Bs, b & 1, b >> 1, value, nullptr,
                                        Wt_val, b_val, b_val, 256, nullptr, v2,
                                        CDIM, CDIM);
    } else {
        const int b2 = b - 512;
        gemm_body<2, false, false, false>(As, Bs, b2 % 3, b2 / 3, query, query_pos,
                                          Wt_qa, b_off, b_attn, 256, nullptr, cbuf,
                                          NCAT, CDIM);
    }
}

// ---------------------------------------------------------------------------
// Output projection: out = tmp @ W_out + b_out + query
// ---------------------------------------------------------------------------
__global__ __launch_bounds__(256, 3) void outproj_k(const bf16_t* __restrict__ tmp,
                                                    const bf16_t* __restrict__ Wt_out,
                                                    const float* __restrict__ b_out,
                                                    const float* __restrict__ query,
                                                    float* __restrict__ out) {
    __shared__ __align__(16) bf16_t As[128][64];
    __shared__ __align__(16) bf16_t Bs[128][64];
    const int b = blockIdx.x;
    gemm_body<0, false, true, false>(As, Bs, b & 1, b >> 1, tmp, nullptr,
                                     Wt_out, b_out, b_out, 256, query, out,
                                     CDIM, CDIM);
}

// ---------------------------------------------------------------------------
// Bilinear sampling with in-register softmax, head-partitioned for XCD-L2.
// v2 layout: (l, h, y, x, 32dh); head = blockIdx % 8 -> one head per XCD.
// Block: 256 threads = 64 queries x 4 dim-chunks of 8. Branchless taps.
// ---------------------------------------------------------------------------
__global__ __launch_bounds__(256) void sample_k(const bf16_t* __restrict__ v2,
                                                const float* __restrict__ cbuf,
                                                const float* __restrict__ refp,
                                                bf16_t* __restrict__ tmp) {
    const int b    = blockIdx.x;
    const int h    = b & 7;          // head -> XCD (round-robin dispatch)
    const int qblk = b >> 3;
    const int tid  = threadIdx.x;
    const int qloc = tid >> 2;
    const int ck   = tid & 3;
    const int q    = qblk * 64 + qloc;

    const float* qrow = cbuf + (size_t)q * NCAT;
    const float4 rp = *reinterpret_cast<const float4*>(refp + (size_t)q * 4);

    // ---- softmax over the 16 logits of (q,h), in-register ----
    const float* attp = qrow + 256 + h * 16;
    float4 A0 = *reinterpret_cast<const float4*>(attp);
    float4 A1 = *reinterpret_cast<const float4*>(attp + 4);
    float4 A2 = *reinterpret_cast<const float4*>(attp + 8);
    float4 A3 = *reinterpret_cast<const float4*>(attp + 12);
    float e[16] = {A0.x, A0.y, A0.z, A0.w, A1.x, A1.y, A1.z, A1.w,
                   A2.x, A2.y, A2.z, A2.w, A3.x, A3.y, A3.z, A3.w};
    float m = e[0];
#pragma unroll
    for (int i = 1; i < 16; ++i) m = fmaxf(m, e[i]);
    float s = 0.f;
#pragma unroll
    for (int i = 0; i < 16; ++i) { e[i] = __expf(e[i] - m); s += e[i]; }
    const float inv = 1.f / s;
#pragma unroll
    for (int i = 0; i < 16; ++i) e[i] *= inv;

    float acc[8] = {0.f, 0.f, 0.f, 0.f, 0.f, 0.f, 0.f, 0.f};

#pragma unroll
    for (int l = 0; l < NLVL; ++l) {
        const float bx = (l == 0 ? rp.x : rp.z) * (float)WWID - 0.5f;
        const float by = (l == 0 ? rp.y : rp.w) * (float)HH - 0.5f;
        const bf16_t* base = v2 + ((size_t)(l * NHEADS + h) * NQ) * DHEAD + ck * 8;
        const float* offp  = qrow + h * 32 + l * 16;

        float4 o0 = *reinterpret_cast<const float4*>(offp);
        float4 o1 = *reinterpret_cast<const float4*>(offp + 4);
        float4 o2 = *reinterpret_cast<const float4*>(offp + 8);
        float4 o3 = *reinterpret_cast<const float4*>(offp + 12);
        const float ox[8] = {o0.x, o0.z, o1.x, o1.z, o2.x, o2.z, o3.x, o3.z};
        const float oy[8] = {o0.y, o0.w, o1.y, o1.w, o2.y, o2.w, o3.y, o3.w};

#pragma unroll
        for (int p = 0; p < NPTS; ++p) {
            const float px = bx + ox[p];
            const float py = by + oy[p];
            const float w  = e[l * 8 + p];
            const float x0f = floorf(px), y0f = floorf(py);
            const int x0 = (int)x0f, y0 = (int)y0f;
            const float wx1 = px - x0f, wy1 = py - y0f;
            const float wx0 = 1.f - wx1, wy0 = 1.f - wy1;
            const bool vx0 = (unsigned)x0 < (unsigned)WWID;
            const bool vx1 = (unsigned)(x0 + 1) < (unsigned)WWID;
            const bool vy0 = (unsigned)y0 < (unsigned)HH;
            const bool vy1 = (unsigned)(y0 + 1) < (unsigned)HH;
            const int xc0 = min(max(x0, 0), WWID - 1);
            const int xc1 = min(max(x0 + 1, 0), WWID - 1);
            const int yc0 = min(max(y0, 0), HH - 1);
            const int yc1 = min(max(y0 + 1, 0), HH - 1);
            const bf16_t* r0 = base + yc0 * (WWID * DHEAD);
            const bf16_t* r1 = base + yc1 * (WWID * DHEAD);
            bf16x8 v00 = *reinterpret_cast<const bf16x8*>(r0 + xc0 * DHEAD);
            bf16x8 v10 = *reinterpret_cast<const bf16x8*>(r0 + xc1 * DHEAD);
            bf16x8 v01 = *reinterpret_cast<const bf16x8*>(r1 + xc0 * DHEAD);
            bf16x8 v11 = *reinterpret_cast<const bf16x8*>(r1 + xc1 * DHEAD);
            const float w00 = (vx0 & vy0) ? w * wx0 * wy0 : 0.f;
            const float w10 = (vx1 & vy0) ? w * wx1 * wy0 : 0.f;
            const float w01 = (vx0 & vy1) ? w * wx0 * wy1 : 0.f;
            const float w11 = (vx1 & vy1) ? w * wx1 * wy1 : 0.f;
#pragma unroll
            for (int i = 0; i < 8; ++i) {
                acc[i] = fmaf(w00, (float)v00[i], acc[i]);
                acc[i] = fmaf(w10, (float)v10[i], acc[i]);
                acc[i] = fmaf(w01, (float)v01[i], acc[i]);
                acc[i] = fmaf(w11, (float)v11[i], acc[i]);
            }
        }
    }

    bf16x8 ov;
#pragma unroll
    for (int i = 0; i < 8; ++i) ov[i] = f2b(acc[i]);
    *reinterpret_cast<bf16x8*>(tmp + (size_t)q * CDIM + h * DHEAD + ck * 8) = ov;
}

// ---------------------------------------------------------------------------
extern "C" void kernel_launch(void* const* d_in, const int* in_sizes, int n_in,
                              void* d_out, int out_size, void* d_ws, size_t ws_size,
                              hipStream_t stream) {
    const float* query     = (const float*)d_in[0];
    const float* query_pos = (const float*)d_in[1];
    const float* value     = (const float*)d_in[2];
    const float* refp      = (const float*)d_in[3];
    // d_in[4] spatial_shapes: static 128x128, hard-coded
    const float* W_off  = (const float*)d_in[5];
    const float* b_off  = (const float*)d_in[6];
    const float* W_attn = (const float*)d_in[7];
    const float* b_attn = (const float*)d_in[8];
    const float* W_val  = (const float*)d_in[9];
    const float* b_val  = (const float*)d_in[10];
    const float* W_out  = (const float*)d_in[11];
    const float* b_out  = (const float*)d_in[12];
    float* out = (float*)d_out;

    char* ws = (char*)d_ws;
    bf16_t* v2      = (bf16_t*)(ws);                      // 16,777,216 B
    float*  cbuf    = (float*)(ws + 16777216);            // 25,165,824 B (16384x384 f32)
    bf16_t* tmp     = (bf16_t*)(ws + 41943040);           //  8,388,608 B
    bf16_t* Wt_val  = (bf16_t*)(ws + 50331648);           //    131,072 B
    bf16_t* Wt_qa   = (bf16_t*)(ws + 50462720);           //    196,608 B (384x256)
    bf16_t* Wt_out  = (bf16_t*)(ws + 50659328);           //    131,072 B
    // total 50,790,400 B

    // all weight transposes in one dispatch
    wtrans_all_k<<<896, 256, 0, stream>>>(W_val, W_off, W_attn, W_out,
                                          Wt_val, Wt_qa, Wt_out);
    // v2 (per-head bf16) + cbuf (off|attn logits) in one dispatch
    fused_proj_k<<<896, 256, 0, stream>>>(value, query, query_pos,
                                          Wt_val, Wt_qa, b_val, b_off, b_attn,
                                          v2, cbuf);
    // softmax (in-register) + bilinear sampling -> tmp (16384 x 256) bf16
    sample_k<<<2048, 256, 0, stream>>>(v2, cbuf, refp, tmp);
    // out = tmp @ W_out + b_out + query (identity)
    outproj_k<<<256, 256, 0, stream>>>(tmp, Wt_out, b_out, query, out);
}

// Round 6
// 211.329 us; speedup vs baseline: 2.7030x; 1.0260x over previous
//
#include <hip/hip_runtime.h>
#include <hip/hip_bf16.h>
#include <math.h>

#define NQ     16384
#define CDIM   256
#define NHEADS 8
#define NPTS   8
#define NLVL   2
#define HH     128
#define WWID   128
#define DHEAD  32
#define NCAT   384   // fused off(256) + attn(128) projection width

typedef __bf16 bf16_t;
typedef __bf16 bf16x8 __attribute__((ext_vector_type(8)));
typedef float  f32x4  __attribute__((ext_vector_type(4)));

typedef __attribute__((address_space(1))) const uint32_t gau32;
typedef __attribute__((address_space(3))) uint32_t lau32;

__device__ __forceinline__ bf16_t f2b(float f) { return (bf16_t)f; }

// ---------------------------------------------------------------------------
// All four weight transposes in ONE dispatch. Wt[n][k] = bf16(W[k][n]), K=256.
// ---------------------------------------------------------------------------
__global__ __launch_bounds__(256) void wtrans_all_k(const float* __restrict__ W_val,
                                                    const float* __restrict__ W_off,
                                                    const float* __restrict__ W_attn,
                                                    const float* __restrict__ W_out,
                                                    bf16_t* __restrict__ Wt_val,
                                                    bf16_t* __restrict__ Wt_qa,
                                                    bf16_t* __restrict__ Wt_out) {
    const int b = blockIdx.x;
    const float* W; bf16_t* Wt; int N, base;
    if (b < 256)      { W = W_val;  Wt = Wt_val;            N = 256; base = 0;   }
    else if (b < 512) { W = W_off;  Wt = Wt_qa;             N = 256; base = 256; }
    else if (b < 640) { W = W_attn; Wt = Wt_qa + 256 * 256; N = 128; base = 512; }
    else              { W = W_out;  Wt = Wt_out;            N = 256; base = 640; }
    int i = (b - base) * 256 + threadIdx.x;   // i = n*256 + k
    int n = i >> 8, k = i & 255;
    if (n >= N) return;
    Wt[i] = f2b(W[(size_t)k * N + n]);
}

// ---------------------------------------------------------------------------
// GEMM body with XOR-swizzled LDS tiles.
// Tile [128 rows][8 granules of 16B]; logical granule g of row r stored at
// physical granule g ^ (r&7). Row stride stays 128 B (global_load_lds
// compatible: wave deposit = 8 rows x 8 granules, lane -> (row=lane>>3,
// phys granule=lane&7), so lane fetches global granule (lane&7)^(lane>>3)).
// This makes ds_write_b128 staging and ds_read_b128 fragment reads uniform
// across all 8 bank-quads (was 32-way / 16-way conflicted).
// ---------------------------------------------------------------------------
template <int A_MODE, bool OUT_BF16, bool ADD_SRC, bool PERM_V>
__device__ __forceinline__ void gemm_body(bf16_t (&As)[128][64], bf16_t (&Bs)[128][64],
                                          int bidx, int bidy,
                                          const void* __restrict__ Aptr,
                                          const void* __restrict__ Aptr2,
                                          const bf16_t* __restrict__ Bt,
                                          const float* __restrict__ bias,
                                          const float* __restrict__ bias2,
                                          int Nsplit,
                                          const float* __restrict__ addsrc,
                                          void* __restrict__ Cout,
                                          int N, int K) {
    const int tid  = threadIdx.x;
    const int wave = tid >> 6;
    const int lane = tid & 63;
    const int rowBase = bidy * 128;
    const int colBase = bidx * 128;
    const int wm = (wave & 1) * 64;
    const int wn = (wave >> 1) * 64;
    const int fr = lane & 15;
    const int fq = lane >> 4;

    f32x4 acc[4][4] = {};

    const int lrow = lane >> 3;                       // 0..7
    const int scol = ((lane & 7) ^ lrow) * 8;         // swizzled k-offset (elems)

    for (int k0 = 0; k0 < K; k0 += 64) {
        __syncthreads();
        if (A_MODE != 0) {
            const int r = tid >> 1, c = tid & 1;
            const float* ap = (const float*)Aptr + (size_t)(rowBase + r) * K + k0 + c * 32;
            const float* ap2 = (A_MODE == 2)
                ? (const float*)Aptr2 + (size_t)(rowBase + r) * K + k0 + c * 32 : nullptr;
#pragma unroll
            for (int u = 0; u < 4; ++u) {
                float4 f0 = *reinterpret_cast<const float4*>(ap + u * 8);
                float4 f1 = *reinterpret_cast<const float4*>(ap + u * 8 + 4);
                if (A_MODE == 2) {
                    float4 g0 = *reinterpret_cast<const float4*>(ap2 + u * 8);
                    float4 g1 = *reinterpret_cast<const float4*>(ap2 + u * 8 + 4);
                    f0.x += g0.x; f0.y += g0.y; f0.z += g0.z; f0.w += g0.w;
                    f1.x += g1.x; f1.y += g1.y; f1.z += g1.z; f1.w += g1.w;
                }
                bf16x8 bv;
                bv[0] = f2b(f0.x); bv[1] = f2b(f0.y); bv[2] = f2b(f0.z); bv[3] = f2b(f0.w);
                bv[4] = f2b(f1.x); bv[5] = f2b(f1.y); bv[6] = f2b(f1.z); bv[7] = f2b(f1.w);
                const int gp = ((c * 4 + u) ^ (r & 7)) * 8;   // swizzled granule
                *reinterpret_cast<bf16x8*>(&As[r][gp]) = bv;
            }
        } else {
            const bf16_t* Abf = (const bf16_t*)Aptr;
#pragma unroll
            for (int t = 0; t < 4; ++t) {
                const bf16_t* src =
                    Abf + (size_t)(rowBase + wave * 32 + t * 8 + lrow) * K + k0 + scol;
                __builtin_amdgcn_global_load_lds((gau32*)src,
                                                 (lau32*)&As[wave * 32 + t * 8][0],
                                                 16, 0, 0);
            }
        }
#pragma unroll
        for (int t = 0; t < 4; ++t) {
            const bf16_t* src =
                Bt + (size_t)(colBase + wave * 32 + t * 8 + lrow) * K + k0 + scol;
            __builtin_amdgcn_global_load_lds((gau32*)src,
                                             (lau32*)&Bs[wave * 32 + t * 8][0],
                                             16, 0, 0);
        }
        __syncthreads();
#pragma unroll
        for (int ks = 0; ks < 2; ++ks) {
            const int gk = ((ks * 4 + fq) ^ (fr & 7)) * 8;  // swizzled read granule
            bf16x8 af[4], bfr[4];
#pragma unroll
            for (int i = 0; i < 4; ++i)
                af[i] = *reinterpret_cast<const bf16x8*>(&As[wm + i * 16 + fr][gk]);
#pragma unroll
            for (int j = 0; j < 4; ++j)
                bfr[j] = *reinterpret_cast<const bf16x8*>(&Bs[wn + j * 16 + fr][gk]);
#pragma unroll
            for (int i = 0; i < 4; ++i)
#pragma unroll
                for (int j = 0; j < 4; ++j)
                    acc[i][j] = __builtin_amdgcn_mfma_f32_16x16x32_bf16(af[i], bfr[j],
                                                                        acc[i][j], 0, 0, 0);
        }
    }

    // epilogue: D[row = fq*4 + r][col = fr] per 16x16 tile
#pragma unroll
    for (int j = 0; j < 4; ++j) {
        const int col = colBase + wn + j * 16 + fr;
        const float bv = (col < Nsplit) ? bias[col] : bias2[col - Nsplit];
#pragma unroll
        for (int i = 0; i < 4; ++i) {
#pragma unroll
            for (int r = 0; r < 4; ++r) {
                const int row = rowBase + wm + i * 16 + fq * 4 + r;
                float vv = acc[i][j][r] + bv;
                if (ADD_SRC) vv += addsrc[(size_t)row * N + col];
                if (PERM_V) {
                    const int l = row >> 14, cell = row & 16383;
                    const size_t dst =
                        (((size_t)(l * NHEADS + (col >> 5)) * NQ + cell) << 5) + (col & 31);
                    ((bf16_t*)Cout)[dst] = f2b(vv);
                } else if (OUT_BF16) {
                    ((bf16_t*)Cout)[(size_t)row * N + col] = f2b(vv);
                } else {
                    ((float*)Cout)[(size_t)row * N + col] = vv;
                }
            }
        }
    }
}

// ---------------------------------------------------------------------------
// Fused projections. Block remap keeps same-row tiles on the SAME XCD
// (ids differing by 8 share rowBase) for A-tile L2 reuse.
// blocks 0..511: v-proj | 512..895: (q+qpos) @ [W_off|W_attn].
// ---------------------------------------------------------------------------
__global__ __launch_bounds__(256, 3) void fused_proj_k(const float* __restrict__ value,
                                                       const float* __restrict__ query,
                                                       const float* __restrict__ query_pos,
                                                       const bf16_t* __restrict__ Wt_val,
                                                       const bf16_t* __restrict__ Wt_qa,
                                                       const float* __restrict__ b_val,
                                                       const float* __restrict__ b_off,
                                                       const float* __restrict__ b_attn,
                                                       bf16_t* __restrict__ v2,
                                                       float* __restrict__ cbuf) {
    __shared__ __align__(16) bf16_t As[128][64];
    __shared__ __align__(16) bf16_t Bs[128][64];
    const int b = blockIdx.x;
    if (b < 512) {
        // 256 rows x 2 cols; b and b+8 share a row (same XCD via %8 dispatch)
        const int bidy = (b >> 4) * 8 + (b & 7);
        const int bidx = (b >> 3) & 1;
        gemm_body<1, true, false, true>(As, Bs, bidx, bidy, value, nullptr,
                                        Wt_val, b_val, b_val, 256, nullptr, v2,
                                        CDIM, CDIM);
    } else {
        // 128 rows x 3 cols; b2, b2+8, b2+16 share a row
        const int b2 = b - 512;
        const int bidy = (b2 / 24) * 8 + (b2 & 7);
        const int bidx = (b2 >> 3) % 3;
        gemm_body<2, false, false, false>(As, Bs, bidx, bidy, query, query_pos,
                                          Wt_qa, b_off, b_attn, 256, nullptr, cbuf,
                                          NCAT, CDIM);
    }
}

// ---------------------------------------------------------------------------
// Output projection: out = tmp @ W_out + b_out + query
// ---------------------------------------------------------------------------
__global__ __launch_bounds__(256, 3) void outproj_k(const bf16_t* __restrict__ tmp,
                                                    const bf16_t* __restrict__ Wt_out,
                                                    const float* __restrict__ b_out,
                                                    const float* __restrict__ query,
                                                    float* __restrict__ out) {
    __shared__ __align__(16) bf16_t As[128][64];
    __shared__ __align__(16) bf16_t Bs[128][64];
    const int b = blockIdx.x;
    const int bidy = (b >> 4) * 8 + (b & 7);   // 128 rows x 2 cols, row-pairs same XCD
    const int bidx = (b >> 3) & 1;
    gemm_body<0, false, true, false>(As, Bs, bidx, bidy, tmp, nullptr,
                                     Wt_out, b_out, b_out, 256, query, out,
                                     CDIM, CDIM);
}

// ---------------------------------------------------------------------------
// Bilinear sampling with in-register softmax, head-partitioned for XCD-L2.
// v2 layout: (l, h, y, x, 32dh); head = blockIdx % 8 -> one head per XCD.
// Block: 256 threads = 64 queries x 4 dim-chunks of 8. Branchless taps.
// ---------------------------------------------------------------------------
__global__ __launch_bounds__(256) void sample_k(const bf16_t* __restrict__ v2,
                                                const float* __restrict__ cbuf,
                                                const float* __restrict__ refp,
                                                bf16_t* __restrict__ tmp) {
    const int b    = blockIdx.x;
    const int h    = b & 7;          // head -> XCD (round-robin dispatch)
    const int qblk = b >> 3;
    const int tid  = threadIdx.x;
    const int qloc = tid >> 2;
    const int ck   = tid & 3;
    const int q    = qblk * 64 + qloc;

    const float* qrow = cbuf + (size_t)q * NCAT;
    const float4 rp = *reinterpret_cast<const float4*>(refp + (size_t)q * 4);

    // ---- softmax over the 16 logits of (q,h), in-register ----
    const float* attp = qrow + 256 + h * 16;
    float4 A0 = *reinterpret_cast<const float4*>(attp);
    float4 A1 = *reinterpret_cast<const float4*>(attp + 4);
    float4 A2 = *reinterpret_cast<const float4*>(attp + 8);
    float4 A3 = *reinterpret_cast<const float4*>(attp + 12);
    float e[16] = {A0.x, A0.y, A0.z, A0.w, A1.x, A1.y, A1.z, A1.w,
                   A2.x, A2.y, A2.z, A2.w, A3.x, A3.y, A3.z, A3.w};
    float m = e[0];
#pragma unroll
    for (int i = 1; i < 16; ++i) m = fmaxf(m, e[i]);
    float s = 0.f;
#pragma unroll
    for (int i = 0; i < 16; ++i) { e[i] = __expf(e[i] - m); s += e[i]; }
    const float inv = 1.f / s;
#pragma unroll
    for (int i = 0; i < 16; ++i) e[i] *= inv;

    float acc[8] = {0.f, 0.f, 0.f, 0.f, 0.f, 0.f, 0.f, 0.f};

#pragma unroll
    for (int l = 0; l < NLVL; ++l) {
        const float bx = (l == 0 ? rp.x : rp.z) * (float)WWID - 0.5f;
        const float by = (l == 0 ? rp.y : rp.w) * (float)HH - 0.5f;
        const bf16_t* base = v2 + ((size_t)(l * NHEADS + h) * NQ) * DHEAD + ck * 8;
        const float* offp  = qrow + h * 32 + l * 16;

        float4 o0 = *reinterpret_cast<const float4*>(offp);
        float4 o1 = *reinterpret_cast<const float4*>(offp + 4);
        float4 o2 = *reinterpret_cast<const float4*>(offp + 8);
        float4 o3 = *reinterpret_cast<const float4*>(offp + 12);
        const float ox[8] = {o0.x, o0.z, o1.x, o1.z, o2.x, o2.z, o3.x, o3.z};
        const float oy[8] = {o0.y, o0.w, o1.y, o1.w, o2.y, o2.w, o3.y, o3.w};

#pragma unroll
        for (int p = 0; p < NPTS; ++p) {
            const float px = bx + ox[p];
            const float py = by + oy[p];
            const float w  = e[l * 8 + p];
            const float x0f = floorf(px), y0f = floorf(py);
            const int x0 = (int)x0f, y0 = (int)y0f;
            const float wx1 = px - x0f, wy1 = py - y0f;
            const float wx0 = 1.f - wx1, wy0 = 1.f - wy1;
            const bool vx0 = (unsigned)x0 < (unsigned)WWID;
            const bool vx1 = (unsigned)(x0 + 1) < (unsigned)WWID;
            const bool vy0 = (unsigned)y0 < (unsigned)HH;
            const bool vy1 = (unsigned)(y0 + 1) < (unsigned)HH;
            const int xc0 = min(max(x0, 0), WWID - 1);
            const int xc1 = min(max(x0 + 1, 0), WWID - 1);
            const int yc0 = min(max(y0, 0), HH - 1);
            const int yc1 = min(max(y0 + 1, 0), HH - 1);
            const bf16_t* r0 = base + yc0 * (WWID * DHEAD);
            const bf16_t* r1 = base + yc1 * (WWID * DHEAD);
            bf16x8 v00 = *reinterpret_cast<const bf16x8*>(r0 + xc0 * DHEAD);
            bf16x8 v10 = *reinterpret_cast<const bf16x8*>(r0 + xc1 * DHEAD);
            bf16x8 v01 = *reinterpret_cast<const bf16x8*>(r1 + xc0 * DHEAD);
            bf16x8 v11 = *reinterpret_cast<const bf16x8*>(r1 + xc1 * DHEAD);
            const float w00 = (vx0 & vy0) ? w * wx0 * wy0 : 0.f;
            const float w10 = (vx1 & vy0) ? w * wx1 * wy0 : 0.f;
            const float w01 = (vx0 & vy1) ? w * wx0 * wy1 : 0.f;
            const float w11 = (vx1 & vy1) ? w * wx1 * wy1 : 0.f;
#pragma unroll
            for (int i = 0; i < 8; ++i) {
                acc[i] = fmaf(w00, (float)v00[i], acc[i]);
                acc[i] = fmaf(w10, (float)v10[i], acc[i]);
                acc[i] = fmaf(w01, (float)v01[i], acc[i]);
                acc[i] = fmaf(w11, (float)v11[i], acc[i]);
            }
        }
    }

    bf16x8 ov;
#pragma unroll
    for (int i = 0; i < 8; ++i) ov[i] = f2b(acc[i]);
    *reinterpret_cast<bf16x8*>(tmp + (size_t)q * CDIM + h * DHEAD + ck * 8) = ov;
}

// ---------------------------------------------------------------------------
extern "C" void kernel_launch(void* const* d_in, const int* in_sizes, int n_in,
                              void* d_out, int out_size, void* d_ws, size_t ws_size,
                              hipStream_t stream) {
    const float* query     = (const float*)d_in[0];
    const float* query_pos = (const float*)d_in[1];
    const float* value     = (const float*)d_in[2];
    const float* refp      = (const float*)d_in[3];
    // d_in[4] spatial_shapes: static 128x128, hard-coded
    const float* W_off  = (const float*)d_in[5];
    const float* b_off  = (const float*)d_in[6];
    const float* W_attn = (const float*)d_in[7];
    const float* b_attn = (const float*)d_in[8];
    const float* W_val  = (const float*)d_in[9];
    const float* b_val  = (const float*)d_in[10];
    const float* W_out  = (const float*)d_in[11];
    const float* b_out  = (const float*)d_in[12];
    float* out = (float*)d_out;

    char* ws = (char*)d_ws;
    bf16_t* v2      = (bf16_t*)(ws);                      // 16,777,216 B
    float*  cbuf    = (float*)(ws + 16777216);            // 25,165,824 B (16384x384 f32)
    bf16_t* tmp     = (bf16_t*)(ws + 41943040);           //  8,388,608 B
    bf16_t* Wt_val  = (bf16_t*)(ws + 50331648);           //    131,072 B
    bf16_t* Wt_qa   = (bf16_t*)(ws + 50462720);           //    196,608 B (384x256)
    bf16_t* Wt_out  = (bf16_t*)(ws + 50659328);           //    131,072 B
    // total 50,790,400 B

    // all weight transposes in one dispatch
    wtrans_all_k<<<896, 256, 0, stream>>>(W_val, W_off, W_attn, W_out,
                                          Wt_val, Wt_qa, Wt_out);
    // v2 (per-head bf16) + cbuf (off|attn logits) in one dispatch
    fused_proj_k<<<896, 256, 0, stream>>>(value, query, query_pos,
                                          Wt_val, Wt_qa, b_val, b_off, b_attn,
                                          v2, cbuf);
    // softmax (in-register) + bilinear sampling -> tmp (16384 x 256) bf16
    sample_k<<<2048, 256, 0, stream>>>(v2, cbuf, refp, tmp);
    // out = tmp @ W_out + b_out + query (identity)
    outproj_k<<<256, 256, 0, stream>>>(tmp, Wt_out, b_out, query, out);
}

// Round 7
// 197.368 us; speedup vs baseline: 2.8942x; 1.0707x over previous
//
#include <hip/hip_runtime.h>
#include <hip/hip_bf16.h>
#include <math.h>

#define NQ     16384
#define CDIM   256
#define NHEADS 8
#define NPTS   8
#define NLVL   2
#define HH     128
#define WWID   128
#define DHEAD  32
#define NCAT   384   // fused off(256) + attn(128) projection width

// padded fp8 value-map geometry: (l, h, 130, 130, 32) fp8, zero border
#define PW        130
#define CELLB     32                    // bytes per cell (32 dims x fp8)
#define ROWB      (PW * CELLB)          // 4160 B per padded row
#define MAPB      (PW * PW * CELLB)     // 540800 B per (l,h) map
#define V2BYTES   (NLVL * NHEADS * MAPB)        // 8,652,800
#define MEMSET_BLKS 2113                // ceil(V2BYTES / (256*16))

typedef __bf16 bf16_t;
typedef __bf16 bf16x8 __attribute__((ext_vector_type(8)));
typedef float  f32x4  __attribute__((ext_vector_type(4)));
typedef float  f32x2  __attribute__((ext_vector_type(2)));

typedef __attribute__((address_space(1))) const uint32_t gau32;
typedef __attribute__((address_space(3))) uint32_t lau32;

__device__ __forceinline__ bf16_t f2b(float f) { return (bf16_t)f; }

// ---------------------------------------------------------------------------
// One dispatch: zero v2 (incl. border) + LDS-transpose all weights to bf16.
// blocks [0, MEMSET_BLKS): memset v2.  Then 224 transpose tiles (32x32).
// ---------------------------------------------------------------------------
__global__ __launch_bounds__(256) void prep_k(const float* __restrict__ W_val,
                                              const float* __restrict__ W_off,
                                              const float* __restrict__ W_attn,
                                              const float* __restrict__ W_out,
                                              unsigned char* __restrict__ v2,
                                              bf16_t* __restrict__ Wt_val,
                                              bf16_t* __restrict__ Wt_qa,
                                              bf16_t* __restrict__ Wt_out) {
    const int b = blockIdx.x;
    if (b < MEMSET_BLKS) {
        size_t off = ((size_t)b * 256 + threadIdx.x) * 16;
        if (off < V2BYTES)
            *reinterpret_cast<uint4*>(v2 + off) = make_uint4(0, 0, 0, 0);
        return;
    }
    const int tb = b - MEMSET_BLKS;
    const float* W; bf16_t* Wt; int N, t;
    if (tb < 64)       { W = W_val;  Wt = Wt_val;            N = 256; t = tb;       }
    else if (tb < 128) { W = W_off;  Wt = Wt_qa;             N = 256; t = tb - 64;  }
    else if (tb < 160) { W = W_attn; Wt = Wt_qa + 256 * 256; N = 128; t = tb - 128; }
    else               { W = W_out;  Wt = Wt_out;            N = 256; t = tb - 160; }
    const int ntn = N >> 5;
    const int k0 = (t / ntn) * 32, n0 = (t % ntn) * 32;
    const int tx = threadIdx.x & 31, ty = threadIdx.x >> 5;   // 32 x 8
    __shared__ float s[32][33];
#pragma unroll
    for (int i = 0; i < 4; ++i)
        s[ty + 8 * i][tx] = W[(size_t)(k0 + ty + 8 * i) * N + n0 + tx];
    __syncthreads();
#pragma unroll
    for (int i = 0; i < 4; ++i)
        Wt[(size_t)(n0 + ty + 8 * i) * 256 + k0 + tx] = f2b(s[tx][ty + 8 * i]);
}

// ---------------------------------------------------------------------------
// GEMM body with XOR-swizzled LDS tiles (conflict-free staging + frag reads).
// A_MODE: 0 = bf16 A (global_load_lds), 1 = fp32 A, 2 = fp32 A + A2 summed.
// PERM_V: epilogue scatters fp8 into the padded per-head v2 map.
// ---------------------------------------------------------------------------
template <int A_MODE, bool OUT_BF16, bool ADD_SRC, bool PERM_V>
__device__ __forceinline__ void gemm_body(bf16_t (&As)[128][64], bf16_t (&Bs)[128][64],
                                          int bidx, int bidy,
                                          const void* __restrict__ Aptr,
                                          const void* __restrict__ Aptr2,
                                          const bf16_t* __restrict__ Bt,
                                          const float* __restrict__ bias,
                                          const float* __restrict__ bias2,
                                          int Nsplit,
                                          const float* __restrict__ addsrc,
                                          void* __restrict__ Cout,
                                          int N, int K) {
    const int tid  = threadIdx.x;
    const int wave = tid >> 6;
    const int lane = tid & 63;
    const int rowBase = bidy * 128;
    const int colBase = bidx * 128;
    const int wm = (wave & 1) * 64;
    const int wn = (wave >> 1) * 64;
    const int fr = lane & 15;
    const int fq = lane >> 4;

    f32x4 acc[4][4] = {};

    const int lrow = lane >> 3;                       // 0..7
    const int scol = ((lane & 7) ^ lrow) * 8;         // swizzled k-offset (elems)

    for (int k0 = 0; k0 < K; k0 += 64) {
        __syncthreads();
        if (A_MODE != 0) {
            const int r = tid >> 1, c = tid & 1;
            const float* ap = (const float*)Aptr + (size_t)(rowBase + r) * K + k0 + c * 32;
            const float* ap2 = (A_MODE == 2)
                ? (const float*)Aptr2 + (size_t)(rowBase + r) * K + k0 + c * 32 : nullptr;
#pragma unroll
            for (int u = 0; u < 4; ++u) {
                float4 f0 = *reinterpret_cast<const float4*>(ap + u * 8);
                float4 f1 = *reinterpret_cast<const float4*>(ap + u * 8 + 4);
                if (A_MODE == 2) {
                    float4 g0 = *reinterpret_cast<const float4*>(ap2 + u * 8);
                    float4 g1 = *reinterpret_cast<const float4*>(ap2 + u * 8 + 4);
                    f0.x += g0.x; f0.y += g0.y; f0.z += g0.z; f0.w += g0.w;
                    f1.x += g1.x; f1.y += g1.y; f1.z += g1.z; f1.w += g1.w;
                }
                bf16x8 bv;
                bv[0] = f2b(f0.x); bv[1] = f2b(f0.y); bv[2] = f2b(f0.z); bv[3] = f2b(f0.w);
                bv[4] = f2b(f1.x); bv[5] = f2b(f1.y); bv[6] = f2b(f1.z); bv[7] = f2b(f1.w);
                const int gp = ((c * 4 + u) ^ (r & 7)) * 8;   // swizzled granule
                *reinterpret_cast<bf16x8*>(&As[r][gp]) = bv;
            }
        } else {
            const bf16_t* Abf = (const bf16_t*)Aptr;
#pragma unroll
            for (int t = 0; t < 4; ++t) {
                const bf16_t* src =
                    Abf + (size_t)(rowBase + wave * 32 + t * 8 + lrow) * K + k0 + scol;
                __builtin_amdgcn_global_load_lds((gau32*)src,
                                                 (lau32*)&As[wave * 32 + t * 8][0],
                                                 16, 0, 0);
            }
        }
#pragma unroll
        for (int t = 0; t < 4; ++t) {
            const bf16_t* src =
                Bt + (size_t)(colBase + wave * 32 + t * 8 + lrow) * K + k0 + scol;
            __builtin_amdgcn_global_load_lds((gau32*)src,
                                             (lau32*)&Bs[wave * 32 + t * 8][0],
                                             16, 0, 0);
        }
        __syncthreads();
#pragma unroll
        for (int ks = 0; ks < 2; ++ks) {
            const int gk = ((ks * 4 + fq) ^ (fr & 7)) * 8;  // swizzled read granule
            bf16x8 af[4], bfr[4];
#pragma unroll
            for (int i = 0; i < 4; ++i)
                af[i] = *reinterpret_cast<const bf16x8*>(&As[wm + i * 16 + fr][gk]);
#pragma unroll
            for (int j = 0; j < 4; ++j)
                bfr[j] = *reinterpret_cast<const bf16x8*>(&Bs[wn + j * 16 + fr][gk]);
#pragma unroll
            for (int i = 0; i < 4; ++i)
#pragma unroll
                for (int j = 0; j < 4; ++j)
                    acc[i][j] = __builtin_amdgcn_mfma_f32_16x16x32_bf16(af[i], bfr[j],
                                                                        acc[i][j], 0, 0, 0);
        }
    }

    // epilogue: D[row = fq*4 + r][col = fr] per 16x16 tile
#pragma unroll
    for (int j = 0; j < 4; ++j) {
        const int col = colBase + wn + j * 16 + fr;
        const float bv = (col < Nsplit) ? bias[col] : bias2[col - Nsplit];
#pragma unroll
        for (int i = 0; i < 4; ++i) {
#pragma unroll
            for (int r = 0; r < 4; ++r) {
                const int row = rowBase + wm + i * 16 + fq * 4 + r;
                float vv = acc[i][j][r] + bv;
                if (ADD_SRC) vv += addsrc[(size_t)row * N + col];
                if (PERM_V) {
                    // row = l*16384 + (y*128+x), col = h*32 + d -> padded fp8 map
                    const int l = row >> 14, cell = row & 16383;
                    const int y = cell >> 7, x = cell & 127;
                    const size_t dst = (size_t)(l * NHEADS + (col >> 5)) * MAPB
                                     + (size_t)(y + 1) * ROWB + (x + 1) * CELLB
                                     + (col & 31);
                    const uint32_t pk = __builtin_amdgcn_cvt_pk_fp8_f32(vv, vv, 0, false);
                    ((unsigned char*)Cout)[dst] = (unsigned char)(pk & 0xff);
                } else if (OUT_BF16) {
                    ((bf16_t*)Cout)[(size_t)row * N + col] = f2b(vv);
                } else {
                    ((float*)Cout)[(size_t)row * N + col] = vv;
                }
            }
        }
    }
}

// ---------------------------------------------------------------------------
// Fused projections. blocks 0..511: v-proj (fp32 -> padded fp8 v2) |
// 512..895: (q+qpos) @ [W_off|W_attn] -> cbuf f32. Row-sharing ids same XCD.
// ---------------------------------------------------------------------------
__global__ __launch_bounds__(256, 3) void fused_proj_k(const float* __restrict__ value,
                                                       const float* __restrict__ query,
                                                       const float* __restrict__ query_pos,
                                                       const bf16_t* __restrict__ Wt_val,
                                                       const bf16_t* __restrict__ Wt_qa,
                                                       const float* __restrict__ b_val,
                                                       const float* __restrict__ b_off,
                                                       const float* __restrict__ b_attn,
                                                       unsigned char* __restrict__ v2,
                                                       float* __restrict__ cbuf) {
    __shared__ __align__(16) bf16_t As[128][64];
    __shared__ __align__(16) bf16_t Bs[128][64];
    const int b = blockIdx.x;
    if (b < 512) {
        const int bidy = (b >> 4) * 8 + (b & 7);
        const int bidx = (b >> 3) & 1;
        gemm_body<1, true, false, true>(As, Bs, bidx, bidy, value, nullptr,
                                        Wt_val, b_val, b_val, 256, nullptr, v2,
                                        CDIM, CDIM);
    } else {
        const int b2 = b - 512;
        const int bidy = (b2 / 24) * 8 + (b2 & 7);
        const int bidx = (b2 >> 3) % 3;
        gemm_body<2, false, false, false>(As, Bs, bidx, bidy, query, query_pos,
                                          Wt_qa, b_off, b_attn, 256, nullptr, cbuf,
                                          NCAT, CDIM);
    }
}

// ---------------------------------------------------------------------------
// Output projection: out = tmp @ W_out + b_out + query
// ---------------------------------------------------------------------------
__global__ __launch_bounds__(256, 3) void outproj_k(const bf16_t* __restrict__ tmp,
                                                    const bf16_t* __restrict__ Wt_out,
                                                    const float* __restrict__ b_out,
                                                    const float* __restrict__ query,
                                                    float* __restrict__ out) {
    __shared__ __align__(16) bf16_t As[128][64];
    __shared__ __align__(16) bf16_t Bs[128][64];
    const int b = blockIdx.x;
    const int bidy = (b >> 4) * 8 + (b & 7);
    const int bidx = (b >> 3) & 1;
    gemm_body<0, false, true, false>(As, Bs, bidx, bidy, tmp, nullptr,
                                     Wt_out, b_out, b_out, 256, query, out,
                                     CDIM, CDIM);
}

// ---------------------------------------------------------------------------
// Bilinear sampling on the zero-padded fp8 map. head = blockIdx % 8 -> XCD.
// Clamp indices into [-1,128]: clamped taps land on zero cells, so corner
// weights apply unconditionally (no bounds selects). fp8 -> f32 via
// v_cvt_pk_f32_fp8 (2 elems/inst), float2 accumulate (v_pk_fma_f32).
// ---------------------------------------------------------------------------
__device__ __forceinline__ void acc_tap(uint2 u, float w, f32x2* acc2) {
    acc2[0] += __builtin_amdgcn_cvt_pk_f32_fp8((int)u.x, false) * w;
    acc2[1] += __builtin_amdgcn_cvt_pk_f32_fp8((int)u.x, true)  * w;
    acc2[2] += __builtin_amdgcn_cvt_pk_f32_fp8((int)u.y, false) * w;
    acc2[3] += __builtin_amdgcn_cvt_pk_f32_fp8((int)u.y, true)  * w;
}

__global__ __launch_bounds__(256) void sample_k(const unsigned char* __restrict__ v2,
                                                const float* __restrict__ cbuf,
                                                const float* __restrict__ refp,
                                                bf16_t* __restrict__ tmp) {
    const int b    = blockIdx.x;
    const int h    = b & 7;          // head -> XCD (round-robin dispatch)
    const int qblk = b >> 3;
    const int tid  = threadIdx.x;
    const int qloc = tid >> 2;
    const int ck   = tid & 3;
    const int q    = qblk * 64 + qloc;

    const float* qrow = cbuf + (size_t)q * NCAT;
    const float4 rp = *reinterpret_cast<const float4*>(refp + (size_t)q * 4);

    // ---- softmax over the 16 logits of (q,h), in-register ----
    const float* attp = qrow + 256 + h * 16;
    float4 A0 = *reinterpret_cast<const float4*>(attp);
    float4 A1 = *reinterpret_cast<const float4*>(attp + 4);
    float4 A2 = *reinterpret_cast<const float4*>(attp + 8);
    float4 A3 = *reinterpret_cast<const float4*>(attp + 12);
    float e[16] = {A0.x, A0.y, A0.z, A0.w, A1.x, A1.y, A1.z, A1.w,
                   A2.x, A2.y, A2.z, A2.w, A3.x, A3.y, A3.z, A3.w};
    float m = e[0];
#pragma unroll
    for (int i = 1; i < 16; ++i) m = fmaxf(m, e[i]);
    float s = 0.f;
#pragma unroll
    for (int i = 0; i < 16; ++i) { e[i] = __expf(e[i] - m); s += e[i]; }
    const float inv = 1.f / s;
#pragma unroll
    for (int i = 0; i < 16; ++i) e[i] *= inv;

    f32x2 acc2[4] = {{0.f, 0.f}, {0.f, 0.f}, {0.f, 0.f}, {0.f, 0.f}};

#pragma unroll
    for (int l = 0; l < NLVL; ++l) {
        const float bx = (l == 0 ? rp.x : rp.z) * (float)WWID - 0.5f;
        const float by = (l == 0 ? rp.y : rp.w) * (float)HH - 0.5f;
        // +131 cells folds the (+1,+1) pad shift into the base
        const unsigned char* base = v2 + (size_t)(l * NHEADS + h) * MAPB
                                       + 131 * CELLB + ck * 8;
        const float* offp = qrow + h * 32 + l * 16;

        float4 o0 = *reinterpret_cast<const float4*>(offp);
        float4 o1 = *reinterpret_cast<const float4*>(offp + 4);
        float4 o2 = *reinterpret_cast<const float4*>(offp + 8);
        float4 o3 = *reinterpret_cast<const float4*>(offp + 12);
        const float ox[8] = {o0.x, o0.z, o1.x, o1.z, o2.x, o2.z, o3.x, o3.z};
        const float oy[8] = {o0.y, o0.w, o1.y, o1.w, o2.y, o2.w, o3.y, o3.w};

#pragma unroll
        for (int p = 0; p < NPTS; ++p) {
            const float px = bx + ox[p];
            const float py = by + oy[p];
            const float w  = e[l * 8 + p];
            const float x0f = floorf(px), y0f = floorf(py);
            const int x0 = (int)x0f, y0 = (int)y0f;
            const float wx1 = px - x0f, wy1 = py - y0f;
            const float wx0 = 1.f - wx1, wy0 = 1.f - wy1;
            const int x0c = min(max(x0, -1), 128);
            const int x1c = min(max(x0 + 1, -1), 128);
            const int y0c = min(max(y0, -1), 128);
            const int y1c = min(max(y0 + 1, -1), 128);
            const unsigned char* r0 = base + y0c * ROWB;
            const unsigned char* r1 = base + y1c * ROWB;
            uint2 u00 = *reinterpret_cast<const uint2*>(r0 + x0c * CELLB);
            uint2 u10 = *reinterpret_cast<const uint2*>(r0 + x1c * CELLB);
            uint2 u01 = *reinterpret_cast<const uint2*>(r1 + x0c * CELLB);
            uint2 u11 = *reinterpret_cast<const uint2*>(r1 + x1c * CELLB);
            const float wy0w = w * wy0, wy1w = w * wy1;
            acc_tap(u00, wy0w * wx0, acc2);
            acc_tap(u10, wy0w * wx1, acc2);
            acc_tap(u01, wy1w * wx0, acc2);
            acc_tap(u11, wy1w * wx1, acc2);
        }
    }

    bf16x8 ov;
#pragma unroll
    for (int i = 0; i < 4; ++i) {
        ov[2 * i]     = f2b(acc2[i].x);
        ov[2 * i + 1] = f2b(acc2[i].y);
    }
    *reinterpret_cast<bf16x8*>(tmp + (size_t)q * CDIM + h * DHEAD + ck * 8) = ov;
}

// ---------------------------------------------------------------------------
extern "C" void kernel_launch(void* const* d_in, const int* in_sizes, int n_in,
                              void* d_out, int out_size, void* d_ws, size_t ws_size,
                              hipStream_t stream) {
    const float* query     = (const float*)d_in[0];
    const float* query_pos = (const float*)d_in[1];
    const float* value     = (const float*)d_in[2];
    const float* refp      = (const float*)d_in[3];
    // d_in[4] spatial_shapes: static 128x128, hard-coded
    const float* W_off  = (const float*)d_in[5];
    const float* b_off  = (const float*)d_in[6];
    const float* W_attn = (const float*)d_in[7];
    const float* b_attn = (const float*)d_in[8];
    const float* W_val  = (const float*)d_in[9];
    const float* b_val  = (const float*)d_in[10];
    const float* W_out  = (const float*)d_in[11];
    const float* b_out  = (const float*)d_in[12];
    float* out = (float*)d_out;

    char* ws = (char*)d_ws;
    unsigned char* v2 = (unsigned char*)(ws);             //  8,654,848 B (padded fp8)
    float*  cbuf    = (float*)(ws + 8654848);             // 25,165,824 B (16384x384 f32)
    bf16_t* tmp     = (bf16_t*)(ws + 33820672);           //  8,388,608 B
    bf16_t* Wt_val  = (bf16_t*)(ws + 42209280);           //    131,072 B
    bf16_t* Wt_qa   = (bf16_t*)(ws + 42340352);           //    196,608 B (384x256)
    bf16_t* Wt_out  = (bf16_t*)(ws + 42536960);           //    131,072 B
    // total 42,668,032 B

    // zero v2 (incl. border) + transpose/convert all weights, one dispatch
    prep_k<<<MEMSET_BLKS + 224, 256, 0, stream>>>(W_val, W_off, W_attn, W_out,
                                                  v2, Wt_val, Wt_qa, Wt_out);
    // v2 (padded fp8 per-head maps) + cbuf (off|attn logits) in one dispatch
    fused_proj_k<<<896, 256, 0, stream>>>(value, query, query_pos,
                                          Wt_val, Wt_qa, b_val, b_off, b_attn,
                                          v2, cbuf);
    // softmax (in-register) + bilinear sampling -> tmp (16384 x 256) bf16
    sample_k<<<2048, 256, 0, stream>>>(v2, cbuf, refp, tmp);
    // out = tmp @ W_out + b_out + query (identity)
    outproj_k<<<256, 256, 0, stream>>>(tmp, Wt_out, b_out, query, out);
}